// Round 1
// baseline (293780.005 us; speedup 1.0000x reference)
//
#include <hip/hip_runtime.h>

// ---------------------------------------------------------------------------
// HandwritingSynthesisNetwork on MI355X.
// Persistent pipelined kernel: per timestep two grid-barrier phases.
//   P1(s): L0 gates+cell (t=s), L1 gates+cell (t=s-1), FC (t=s-2)
//   P2(s): ATT (t=s), L2 gates+cell (t=s-1)
// All blocks cover all j (output-dim partition, all 64 batches in-block) so
// every weight element is read exactly once per phase chip-wide.
// Cell states in registers; h/w flow through depth-4 fp32 rings in ws.
// ---------------------------------------------------------------------------

#define TT   800
#define BB   64
#define UU   100
#define VV   80
#define HH   512
#define KAA  10
#define NOUT 121
#define K0P  596     // 3+80+512 (+1 zero pad)
#define K12P 1108    // 3+80+512+512 (+1 zero pad)
#define KFC  1536

// ws layout (float offsets)
#define OFF_ST    64                        // strokesT [T][3][64]
#define OFF_H0    (OFF_ST + TT*3*BB)        // h0 ring [4][512][64]
#define OFF_H1    (OFF_H0 + 4*HH*BB)
#define OFF_H2    (OFF_H1 + 4*HH*BB)
#define OFF_WR    (OFF_H2 + 4*HH*BB)        // w ring [4][80][64]
#define OFF_KAP   (OFF_WR + 4*VV*BB)        // kappa [64][10]
#define OFF_W0P   (OFF_KAP + BB*KAA)        // packed [2048][596]
#define OFF_W1P   (OFF_W0P + 2048*K0P)      // packed [2048][1108]
#define OFF_W2P   (OFF_W1P + 2048*K12P)
#define WS_FLOATS (OFF_W2P + 2048*K12P)     // ~25.3 MB

__device__ __forceinline__ float sigmf(float x) { return 1.f / (1.f + __expf(-x)); }
__device__ __forceinline__ float tanhf_(float x) { return 1.f - 2.f / (1.f + __expf(2.f * x)); }

// --------------------------- prep kernels ----------------------------------
__global__ void prep_zero(float* __restrict__ ws) {
    int i = blockIdx.x * blockDim.x + threadIdx.x;
    if (i < 64) ws[i] = 0.f;                 // barrier words
    int j = i - 64;
    if (j >= 0 && j < (3 * 4 * HH * BB + 4 * VV * BB + BB * KAA))
        ws[OFF_H0 + j] = 0.f;                // rings + kappa
}

__global__ void prep_strokesT(const float* __restrict__ strokes, float* __restrict__ ws) {
    int idx = blockIdx.x * blockDim.x + threadIdx.x;
    if (idx >= TT * 3 * BB) return;
    int b = idx & 63;
    int tk = idx >> 6;
    int k = tk % 3, t = tk / 3;
    ws[OFF_ST + idx] = strokes[((size_t)b * TT + t) * 3 + k];
}

// dst[2048][kpad] row = [Wih row (kin) | Whh row (512) | zeros]
__global__ void prep_wpack(const float* __restrict__ Wih, const float* __restrict__ Whh,
                           float* __restrict__ dst, int kin, int kpad) {
    int idx = blockIdx.x * blockDim.x + threadIdx.x;
    if (idx >= 2048 * kpad) return;
    int row = idx / kpad, col = idx - row * kpad;
    float v = 0.f;
    if (col < kin)            v = Wih[(size_t)row * kin + col];
    else if (col < kin + 512) v = Whh[(size_t)row * 512 + (col - kin)];
    dst[idx] = v;
}

// --------------------------- grid barrier ----------------------------------
__device__ void gbar(unsigned* bar, unsigned nblk) {
    __syncthreads();
    if (threadIdx.x == 0) {
        __threadfence();   // release my writes device-wide
        unsigned* cnt = bar;
        unsigned* gen = bar + 16;
        unsigned g = __hip_atomic_load(gen, __ATOMIC_RELAXED, __HIP_MEMORY_SCOPE_AGENT);
        unsigned old = __hip_atomic_fetch_add(cnt, 1u, __ATOMIC_ACQ_REL, __HIP_MEMORY_SCOPE_AGENT);
        if (old == nblk - 1) {
            __hip_atomic_store(cnt, 0u, __ATOMIC_RELAXED, __HIP_MEMORY_SCOPE_AGENT);
            __hip_atomic_fetch_add(gen, 1u, __ATOMIC_RELEASE, __HIP_MEMORY_SCOPE_AGENT);
        } else {
            while (__hip_atomic_load(gen, __ATOMIC_RELAXED, __HIP_MEMORY_SCOPE_AGENT) == g)
                __builtin_amdgcn_s_sleep(2);
        }
        __threadfence();   // acquire others' writes
    }
    __syncthreads();
}

// --------------------------- main pipeline ---------------------------------
__global__ void __launch_bounds__(256)
hand_pipeline(const int* __restrict__ chars, const float* __restrict__ chars_mask,
              const float* __restrict__ W_att, const float* __restrict__ b_att,
              const float* __restrict__ pb0, const float* __restrict__ pb1,
              const float* __restrict__ pb2, const float* __restrict__ W_fc,
              const float* __restrict__ b_fc, float* __restrict__ ws,
              float* __restrict__ out) {
    __shared__ float smem[16640];       // 2x [128][64] chunk bufs + FC xf + scratch
    const int tid  = threadIdx.x;
    const int blk  = blockIdx.x;
    unsigned* bar  = (unsigned*)ws;

    const int cell = tid & 127;
    const int b    = cell & 63;
    const int jloc = cell >> 6;
    const int j    = blk * 2 + jloc;    // 256 blocks x 2 = all 512 j

    float cA = 0.f;   // L0 state (tid<128) or L1 state (tid>=128)
    float cB = 0.f;   // L2 state (tid<128)

    float* sA = smem;          // [128][64]
    float* sB = smem + 8192;   // [128][64]

    for (int s = 0; s <= TT + 1; ++s) {
        // =============== P1: L0(t=s), L1(t=s-1), FC(t=s-2) ==================
        const bool a0 = (s < TT);
        const bool a1 = (s >= 1 && s <= TT);
        const bool af = (s >= 2);
        {
            const int sl  = (s - 1) & 3;   // w[s-1], h0[s-1]
            const int sl2 = (s - 2) & 3;   // h1[s-2]
            float acc[4] = {0.f, 0.f, 0.f, 0.f};
            if (tid < 128) {
                if (a0) {
#pragma unroll
                    for (int g = 0; g < 4; ++g) acc[g] = pb0[g * HH + j];
                }
            } else {
                if (a1) {
#pragma unroll
                    for (int g = 0; g < 4; ++g) acc[g] = pb1[g * HH + j];
                }
            }
            for (int c = 0; c < 9; ++c) {
                const int r0 = c * 128;
                if (a0 && c < 5) {   // stage x0 chunk: [strokes|w|h0|pad]
                    const int nr = min(128, K0P - r0);
                    for (int fl = tid; fl < nr * 64; fl += 256) {
                        int bb = fl & 63, r = r0 + (fl >> 6);
                        float v = 0.f;
                        if (r < 3)        v = ws[OFF_ST + s * 192 + r * 64 + bb];
                        else if (r < 83)  v = ws[OFF_WR + sl * (VV * BB) + (r - 3) * 64 + bb];
                        else if (r < 595) v = ws[OFF_H0 + sl * (HH * BB) + (r - 83) * 64 + bb];
                        sA[fl] = v;
                    }
                }
                if (a1) {            // stage x1 chunk: [strokes|w|h0|h1prev|pad], t=s-1
                    const int nr = min(128, K12P - r0);
                    for (int fl = tid; fl < nr * 64; fl += 256) {
                        int bb = fl & 63, r = r0 + (fl >> 6);
                        float v = 0.f;
                        if (r < 3)         v = ws[OFF_ST + (s - 1) * 192 + r * 64 + bb];
                        else if (r < 83)   v = ws[OFF_WR + sl * (VV * BB) + (r - 3) * 64 + bb];
                        else if (r < 595)  v = ws[OFF_H0 + sl * (HH * BB) + (r - 83) * 64 + bb];
                        else if (r < 1107) v = ws[OFF_H1 + sl2 * (HH * BB) + (r - 595) * 64 + bb];
                        sB[fl] = v;
                    }
                }
                __syncthreads();
                if (tid < 128) {
                    if (a0 && c < 5) {
                        const int nr = min(128, K0P - r0);
                        const float* w0 = ws + OFF_W0P + (size_t)j * K0P + r0;
                        for (int kk = 0; kk < nr; kk += 4) {
                            float x0 = sA[kk * 64 + b],       x1 = sA[(kk + 1) * 64 + b];
                            float x2 = sA[(kk + 2) * 64 + b], x3 = sA[(kk + 3) * 64 + b];
#pragma unroll
                            for (int g = 0; g < 4; ++g) {
                                const float4 wv = *(const float4*)(w0 + (size_t)g * (HH * K0P) + kk);
                                acc[g] = fmaf(x0, wv.x, fmaf(x1, wv.y, fmaf(x2, wv.z, fmaf(x3, wv.w, acc[g]))));
                            }
                        }
                    }
                } else {
                    if (a1) {
                        const int nr = min(128, K12P - r0);
                        const float* w1 = ws + OFF_W1P + (size_t)j * K12P + r0;
                        for (int kk = 0; kk < nr; kk += 4) {
                            float x0 = sB[kk * 64 + b],       x1 = sB[(kk + 1) * 64 + b];
                            float x2 = sB[(kk + 2) * 64 + b], x3 = sB[(kk + 3) * 64 + b];
#pragma unroll
                            for (int g = 0; g < 4; ++g) {
                                const float4 wv = *(const float4*)(w1 + (size_t)g * (HH * K12P) + kk);
                                acc[g] = fmaf(x0, wv.x, fmaf(x1, wv.y, fmaf(x2, wv.z, fmaf(x3, wv.w, acc[g]))));
                            }
                        }
                    }
                }
                __syncthreads();
            }
            if (tid < 128) {       // L0 cell update -> h0 ring
                if (a0) {
                    float ig = sigmf(acc[0]), fg = sigmf(acc[1]);
                    float gg = tanhf_(acc[2]), og = sigmf(acc[3]);
                    cA = fg * cA + ig * gg;
                    ws[OFF_H0 + (s & 3) * (HH * BB) + j * 64 + b] = og * tanhf_(cA);
                }
            } else {               // L1 cell update -> h1 ring
                if (a1) {
                    float ig = sigmf(acc[0]), fg = sigmf(acc[1]);
                    float gg = tanhf_(acc[2]), og = sigmf(acc[3]);
                    cA = fg * cA + ig * gg;
                    ws[OFF_H1 + ((s - 1) & 3) * (HH * BB) + j * 64 + b] = og * tanhf_(cA);
                }
            }
        }
        // FC(t=s-2) on blocks 128..255: idx -> (bgroup of 8 b) x (ochunk of 8)
        if (af && blk >= 128) {
            __syncthreads();
            const int slf = (s - 2) & 3;
            const int idx = blk - 128;
            const int bg = idx & 7, oc = idx >> 3;
            for (int fl = tid; fl < KFC * 8; fl += 256) {   // xf [1536][8]
                int bl = fl & 7, k = fl >> 3;
                int bb = bg * 8 + bl;
                float v;
                if (k < 512)       v = ws[OFF_H0 + slf * (HH * BB) + k * 64 + bb];
                else if (k < 1024) v = ws[OFF_H1 + slf * (HH * BB) + (k - 512) * 64 + bb];
                else               v = ws[OFF_H2 + slf * (HH * BB) + (k - 1024) * 64 + bb];
                smem[fl] = v;
            }
            __syncthreads();
            const int cf = tid & 63, kp = tid >> 6;
            const int bl = cf & 7, ol = cf >> 3;
            const int o = oc * 8 + ol;
            float fa = 0.f;
            if (o < NOUT) {
                const float* wf = W_fc + (size_t)o * KFC + kp * 384;
                for (int k = 0; k < 384; k += 4) {
                    float4 wv = *(const float4*)(wf + k);
                    int kb = (kp * 384 + k) * 8 + bl;
                    fa = fmaf(smem[kb], wv.x, fmaf(smem[kb + 8], wv.y,
                         fmaf(smem[kb + 16], wv.z, fmaf(smem[kb + 24], wv.w, fa))));
                }
            }
            float* fcred = smem + 12288;
            if (kp > 0) fcred[(kp - 1) * 64 + cf] = fa;
            __syncthreads();
            if (kp == 0 && o < NOUT) {
                fa += fcred[cf] + fcred[64 + cf] + fcred[128 + cf] + b_fc[o];
                out[((size_t)(bg * 8 + bl) * TT + (s - 2)) * NOUT + o] = fa;
            }
        }
        gbar(bar, gridDim.x);

        // =============== P2: ATT(t=s), L2(t=s-1) ============================
        const bool a2 = (s >= 1 && s <= TT);
        const bool aa = (s < TT);
        {
            const int sl  = (s - 1) & 3;   // w[s-1], h1[s-1]
            const int sl2 = (s - 2) & 3;   // h2[s-2]
            const int kh  = tid >> 7;      // K-half split: kh0 -> k<512, kh1 -> k in [512,1108)
            float acc[4] = {0.f, 0.f, 0.f, 0.f};
            if (a2 && kh == 0) {
#pragma unroll
                for (int g = 0; g < 4; ++g) acc[g] = pb2[g * HH + j];
            }
            for (int c = 0; c < 9; ++c) {
                const int r0 = c * 128;
                if (a2) {   // stage x2 chunk: [strokes|w|h1|h2prev|pad], t=s-1
                    const int nr = min(128, K12P - r0);
                    for (int fl = tid; fl < nr * 64; fl += 256) {
                        int bb = fl & 63, r = r0 + (fl >> 6);
                        float v = 0.f;
                        if (r < 3)         v = ws[OFF_ST + (s - 1) * 192 + r * 64 + bb];
                        else if (r < 83)   v = ws[OFF_WR + sl * (VV * BB) + (r - 3) * 64 + bb];
                        else if (r < 595)  v = ws[OFF_H1 + sl * (HH * BB) + (r - 83) * 64 + bb];
                        else if (r < 1107) v = ws[OFF_H2 + sl2 * (HH * BB) + (r - 595) * 64 + bb];
                        sA[fl] = v;
                    }
                }
                __syncthreads();
                if (a2 && ((kh == 0 && c < 4) || (kh == 1 && c >= 4))) {
                    const int nr = min(128, K12P - r0);
                    const float* w2 = ws + OFF_W2P + (size_t)j * K12P + r0;
                    for (int kk = 0; kk < nr; kk += 4) {
                        float x0 = sA[kk * 64 + b],       x1 = sA[(kk + 1) * 64 + b];
                        float x2 = sA[(kk + 2) * 64 + b], x3 = sA[(kk + 3) * 64 + b];
#pragma unroll
                        for (int g = 0; g < 4; ++g) {
                            const float4 wv = *(const float4*)(w2 + (size_t)g * (HH * K12P) + kk);
                            acc[g] = fmaf(x0, wv.x, fmaf(x1, wv.y, fmaf(x2, wv.z, fmaf(x3, wv.w, acc[g]))));
                        }
                    }
                }
                __syncthreads();
            }
            if (a2 && kh == 1) {
#pragma unroll
                for (int g = 0; g < 4; ++g) sB[cell * 4 + g] = acc[g];
            }
            __syncthreads();
            if (a2 && kh == 0) {
#pragma unroll
                for (int g = 0; g < 4; ++g) acc[g] += sB[cell * 4 + g];
                float ig = sigmf(acc[0]), fg = sigmf(acc[1]);
                float gg = tanhf_(acc[2]), og = sigmf(acc[3]);
                cB = fg * cB + ig * gg;
                ws[OFF_H2 + ((s - 1) & 3) * (HH * BB) + j * 64 + b] = og * tanhf_(cB);
            }
            // ---- attention for t=s on blocks 0..63 (block = batch) ----
            if (aa && blk < 64) {
                __syncthreads();
                const int ab = blk;
                float* hcol = smem;          // 512
                float* abk  = smem + 512;    // 30: exp(alpha|beta|kappa)
                float* kap  = smem + 544;    // 10
                float* phi  = smem + 560;    // 100
                float* msk  = smem + 660;    // 100
                int*   chs  = (int*)(smem + 760);  // 100
                hcol[tid]       = ws[OFF_H0 + (s & 3) * (HH * BB) + tid * 64 + ab];
                hcol[tid + 256] = ws[OFF_H0 + (s & 3) * (HH * BB) + (tid + 256) * 64 + ab];
                if (tid < 100) {
                    chs[tid] = chars[ab * UU + tid];
                    msk[tid] = chars_mask[ab * UU + tid];
                }
                __syncthreads();
                int a = tid >> 3, p = tid & 7;
                if (a < 30) {
                    float pa = 0.f;
                    const float* wa = W_att + a * HH + p * 64;
                    for (int n = 0; n < 64; ++n) pa = fmaf(hcol[p * 64 + n], wa[n], pa);
                    pa += __shfl_down(pa, 4, 8);
                    pa += __shfl_down(pa, 2, 8);
                    pa += __shfl_down(pa, 1, 8);
                    if (p == 0) abk[a] = __expf(pa + b_att[a]);
                }
                __syncthreads();
                if (tid < 10) {
                    float kv = abk[20 + tid] * 0.05f + ws[OFF_KAP + ab * KAA + tid];
                    ws[OFF_KAP + ab * KAA + tid] = kv;
                    kap[tid] = kv;
                }
                __syncthreads();
                if (tid < 100) {
                    float u = (float)tid, ph = 0.f;
#pragma unroll
                    for (int ka = 0; ka < 10; ++ka) {
                        float d = kap[ka] - u;
                        ph += abk[ka] * __expf(-abk[10 + ka] * d * d);
                    }
                    phi[tid] = ph * msk[tid];   // phi *= mask (as in reference)
                }
                __syncthreads();
                if (tid < 80) {
                    float wv = 0.f;
                    for (int u2 = 0; u2 < 100; ++u2)
                        if (chs[u2] == tid) wv += phi[u2] * msk[u2];  // ctx also carries mask
                    ws[OFF_WR + (s & 3) * (VV * BB) + tid * 64 + ab] = wv;
                }
            }
        }
        gbar(bar, gridDim.x);
    }
}

// ------------------------ output postprocessing ----------------------------
// raw fc row [mu(40)|log_sigma(40)|pi(20)|rho(20)|eos(1)] ->
// packed [log_pi(20)|mu(40)|log_sigma(40)|tanh(rho)(20)|sigmoid(-eos)(1)], in place.
__global__ void postproc_kernel(float* __restrict__ out) {
    int row  = blockIdx.x * 8 + (threadIdx.x >> 5);
    int lane = threadIdx.x & 31;
    float* r = out + (size_t)row * NOUT;
    float pv = (lane < 20) ? r[80 + lane] : -1e30f;
    float m = pv;
#pragma unroll
    for (int off = 16; off; off >>= 1) m = fmaxf(m, __shfl_xor(m, off, 32));
    float e = (lane < 20) ? __expf(pv - m) : 0.f;
    float sm = e;
#pragma unroll
    for (int off = 16; off; off >>= 1) sm += __shfl_xor(sm, off, 32);
    float logZ = m + __logf(sm);
    float res[4];
    bool wr[4];
    int ps[4];
#pragma unroll
    for (int i = 0; i < 4; ++i) {
        int p = lane + 32 * i;
        ps[i] = p;
        wr[i] = (p < NOUT);
        float x = 0.f;
        if (p < 20)       x = pv - logZ;
        else if (p < 100) { if (wr[i]) x = r[p - 20]; }
        else if (p < 120) x = tanhf_(r[p]);
        else if (p == 120) x = 1.f / (1.f + __expf(r[120]));
        res[i] = x;
    }
#pragma unroll
    for (int i = 0; i < 4; ++i)
        if (wr[i]) r[ps[i]] = res[i];
}

// ------------------------------- launcher ----------------------------------
extern "C" void kernel_launch(void* const* d_in, const int* in_sizes, int n_in,
                              void* d_out, int out_size, void* d_ws, size_t ws_size,
                              hipStream_t stream) {
    const int*   chars      = (const int*)d_in[0];
    const float* chars_mask = (const float*)d_in[1];
    const float* strokes    = (const float*)d_in[2];
    const float* W_ih0 = (const float*)d_in[4];
    const float* W_hh0 = (const float*)d_in[5];
    const float* b0    = (const float*)d_in[6];
    const float* W_att = (const float*)d_in[7];
    const float* b_att = (const float*)d_in[8];
    const float* W_ih1 = (const float*)d_in[9];
    const float* W_hh1 = (const float*)d_in[10];
    const float* b1    = (const float*)d_in[11];
    const float* W_ih2 = (const float*)d_in[12];
    const float* W_hh2 = (const float*)d_in[13];
    const float* b2    = (const float*)d_in[14];
    const float* W_fc  = (const float*)d_in[15];
    const float* b_fc  = (const float*)d_in[16];
    float* ws  = (float*)d_ws;
    float* out = (float*)d_out;

    const int nz = 64 + 3 * 4 * HH * BB + 4 * VV * BB + BB * KAA;
    prep_zero<<<(nz + 255) / 256, 256, 0, stream>>>(ws);
    prep_strokesT<<<(TT * 3 * BB + 255) / 256, 256, 0, stream>>>(strokes, ws);
    prep_wpack<<<(2048 * K0P + 255) / 256, 256, 0, stream>>>(W_ih0, W_hh0, ws + OFF_W0P, 83, K0P);
    prep_wpack<<<(2048 * K12P + 255) / 256, 256, 0, stream>>>(W_ih1, W_hh1, ws + OFF_W1P, 595, K12P);
    prep_wpack<<<(2048 * K12P + 255) / 256, 256, 0, stream>>>(W_ih2, W_hh2, ws + OFF_W2P, 595, K12P);

    // 256 blocks (1/CU; LDS 65KB => >=2 blocks/CU possible) -> all co-resident.
    hand_pipeline<<<256, 256, 0, stream>>>(chars, chars_mask, W_att, b_att,
                                           b0, b1, b2, W_fc, b_fc, ws, out);
    postproc_kernel<<<(BB * TT) / 8, 256, 0, stream>>>(out);
}

// Round 3
// 69742.651 us; speedup vs baseline: 4.2123x; 4.2123x over previous
//
#include <hip/hip_runtime.h>

// ---------------------------------------------------------------------------
// HandwritingSynthesisNetwork on MI355X — round 3 (round-2 structure, OOB fixes).
// Persistent kernel, 256 blocks x 1024 threads (16 waves/CU), 2 grid-barrier
// phases per timestep:
//   P1(s): L0 gates (t=s) + L1 gates (t=s-1)   [shared-x job JA + JB + JC]
//   P2(s): L2 gates (t=s-1) + FC (t=s-2) + ATT (t=s)
// wave = 64 batch lanes; waves own k-slices; x read directly from global
// rings (coalesced 256B); weights wave-uniform from packed L2-resident
// arrays; partials reduced via LDS once per phase.
// Fixes vs round 2: (a) W_fc second-output pointer clamped in-bounds for
// blk=124 (read 6KB past end -> fault); (b) JB k-range clamped to 516 rows
// (3+1+512), prep_wb zero-pads k>=516; (c) barrier gen load ACQUIRE.
// ---------------------------------------------------------------------------

#define TT   800
#define BB   64
#define UU   100
#define VV   80
#define HH   512
#define NOUT 121

// ---- ws layout (float offsets) ----
#define OFF_ST   1024                        // strokesT [T][3][64]
#define OFF_H0   (OFF_ST + TT*3*BB)          // rings [4][512][64]
#define OFF_H1   (OFF_H0 + 4*HH*BB)
#define OFF_H2   (OFF_H1 + 4*HH*BB)
#define OFF_WR   (OFF_H2 + 4*HH*BB)          // w ring [4][80][64]
#define OFF_WA   (OFF_WR + 4*VV*BB)          // packed JA weights [256][592][16]
#define OFF_WB   (OFF_WA + 256*592*16)       // [256][520][8]
#define OFF_WC   (OFF_WB + 256*520*8)        // [256][4][8]
#define OFF_WD   (OFF_WC + 256*4*8)          // [256][1108][8]

// ---- LDS layout (float offsets) ----
#define L_REDA  0        // 11 x 16 x 64 = 11264  (P2: 16 x 8 x 64 = 8192)
#define L_REDB  11264    // 5 x 8 x 64 = 2560     (P2 FC: 16 x 2 x 64 = 2048)
#define L_REDC  13824    // 8 x 64 = 512
#define L_GATES 14336    // 16 x 64 = 1024
#define L_WATT  15360    // 30 x 512 = 15360
#define L_HCOL  30720    // 512
#define L_ABK   31232    // 32
#define L_KAP   31264    // 16
#define L_PHI   31280    // 112
#define L_MSK   31392    // 112
#define L_CHS   31504    // 112
#define L_TOT   31616

__device__ __forceinline__ float sigmf(float x) { return 1.f / (1.f + __expf(-x)); }
__device__ __forceinline__ float tanhf_(float x) { return 1.f - 2.f / (1.f + __expf(2.f * x)); }

// 8 output rows, weights W[k][8], x = X[k*64+b]
__device__ __forceinline__ void run8(float* acc, const float* __restrict__ W,
                                     const float* X, int k0, int k1, int b) {
#pragma unroll 4
    for (int k = k0; k < k1; ++k) {
        const float x = X[k * 64 + b];
        const float4 w0 = *(const float4*)(W + (size_t)k * 8);
        const float4 w1 = *(const float4*)(W + (size_t)k * 8 + 4);
        acc[0] = fmaf(x, w0.x, acc[0]); acc[1] = fmaf(x, w0.y, acc[1]);
        acc[2] = fmaf(x, w0.z, acc[2]); acc[3] = fmaf(x, w0.w, acc[3]);
        acc[4] = fmaf(x, w1.x, acc[4]); acc[5] = fmaf(x, w1.y, acc[5]);
        acc[6] = fmaf(x, w1.z, acc[6]); acc[7] = fmaf(x, w1.w, acc[7]);
    }
}

// 16 output rows, weights W[k][16]
__device__ __forceinline__ void run16(float* acc, const float* __restrict__ W,
                                      const float* X, int k0, int k1, int b) {
#pragma unroll 2
    for (int k = k0; k < k1; ++k) {
        const float x = X[k * 64 + b];
        const float4* wp = (const float4*)(W + (size_t)k * 16);
        const float4 w0 = wp[0], w1 = wp[1], w2 = wp[2], w3 = wp[3];
        acc[0]  = fmaf(x, w0.x, acc[0]);  acc[1]  = fmaf(x, w0.y, acc[1]);
        acc[2]  = fmaf(x, w0.z, acc[2]);  acc[3]  = fmaf(x, w0.w, acc[3]);
        acc[4]  = fmaf(x, w1.x, acc[4]);  acc[5]  = fmaf(x, w1.y, acc[5]);
        acc[6]  = fmaf(x, w1.z, acc[6]);  acc[7]  = fmaf(x, w1.w, acc[7]);
        acc[8]  = fmaf(x, w2.x, acc[8]);  acc[9]  = fmaf(x, w2.y, acc[9]);
        acc[10] = fmaf(x, w2.z, acc[10]); acc[11] = fmaf(x, w2.w, acc[11]);
        acc[12] = fmaf(x, w3.x, acc[12]); acc[13] = fmaf(x, w3.y, acc[13]);
        acc[14] = fmaf(x, w3.z, acc[14]); acc[15] = fmaf(x, w3.w, acc[15]);
    }
}

// --------------------------- prep kernels ----------------------------------
__global__ void prep_zero(float* __restrict__ ws) {
    int i = blockIdx.x * blockDim.x + threadIdx.x;
    if (i < 1024) ws[i] = 0.f;                       // barrier words
    int j = i - 1024;
    if (j >= 0 && j < (3 * 4 * HH * BB + 4 * VV * BB))
        ws[OFF_H0 + j] = 0.f;                        // rings
}

__global__ void prep_strokesT(const float* __restrict__ strokes, float* __restrict__ ws) {
    int idx = blockIdx.x * blockDim.x + threadIdx.x;
    if (idx >= TT * 3 * BB) return;
    int b = idx & 63;
    int tk = idx >> 6;
    int k = tk % 3, t = tk / 3;
    ws[OFF_ST + idx] = strokes[((size_t)b * TT + t) * 3 + k];
}

// JA: [blk][k<592][c<16]  c<8: L0 (w|h0 cols), c>=8: L1 (w|h0 cols)
__global__ void prep_wa(const float* __restrict__ Wih0, const float* __restrict__ Whh0,
                        const float* __restrict__ Wih1, float* __restrict__ dst) {
    int idx = blockIdx.x * blockDim.x + threadIdx.x;
    if (idx >= 256 * 592 * 16) return;
    int c = idx & 15, k = (idx >> 4) % 592, blk = idx / (592 * 16);
    int hu = (c >> 2) & 1, g = c & 3;
    int grow = g * HH + blk * 2 + hu;
    float v;
    if (c < 8) v = (k < 80) ? Wih0[(size_t)grow * 83 + 3 + k] : Whh0[(size_t)grow * 512 + (k - 80)];
    else       v = (k < 80) ? Wih1[(size_t)grow * 595 + 3 + k] : Wih1[(size_t)grow * 595 + 83 + (k - 80)];
    dst[idx] = v;
}

// JB: [blk][k<520][c<8]  L1: k<3 strokes, k==3 pad, 4<=k<516 Whh1, k>=516 pad
__global__ void prep_wb(const float* __restrict__ Wih1, const float* __restrict__ Whh1,
                        float* __restrict__ dst) {
    int idx = blockIdx.x * blockDim.x + threadIdx.x;
    if (idx >= 256 * 520 * 8) return;
    int c = idx & 7, k = (idx >> 3) % 520, blk = idx / (520 * 8);
    int hu = c >> 2, g = c & 3;
    int grow = g * HH + blk * 2 + hu;
    float v = 0.f;
    if (k < 3) v = Wih1[(size_t)grow * 595 + k];
    else if (k >= 4 && k < 516) v = Whh1[(size_t)grow * 512 + (k - 4)];
    dst[idx] = v;
}

// JC: [blk][k<4][c<8]  L0 strokes cols
__global__ void prep_wc(const float* __restrict__ Wih0, float* __restrict__ dst) {
    int idx = blockIdx.x * blockDim.x + threadIdx.x;
    if (idx >= 256 * 4 * 8) return;
    int c = idx & 7, k = (idx >> 3) & 3, blk = idx / 32;
    int hu = c >> 2, g = c & 3;
    int grow = g * HH + blk * 2 + hu;
    dst[idx] = (k < 3) ? Wih0[(size_t)grow * 83 + k] : 0.f;
}

// JD: [blk][k<1108][c<8]  L2: strokes|pad|w|h1|h2
__global__ void prep_wd(const float* __restrict__ Wih2, const float* __restrict__ Whh2,
                        float* __restrict__ dst) {
    int idx = blockIdx.x * blockDim.x + threadIdx.x;
    if (idx >= 256 * 1108 * 8) return;
    int c = idx & 7, k = (idx >> 3) % 1108, blk = idx / (1108 * 8);
    int hu = c >> 2, g = c & 3;
    int grow = g * HH + blk * 2 + hu;
    float v = 0.f;
    if (k < 3) v = Wih2[(size_t)grow * 595 + k];
    else if (k >= 4 && k < 84) v = Wih2[(size_t)grow * 595 + 3 + (k - 4)];
    else if (k >= 84 && k < 596) v = Wih2[(size_t)grow * 595 + 83 + (k - 84)];
    else if (k >= 596) v = Whh2[(size_t)grow * 512 + (k - 596)];
    dst[idx] = v;
}

// --------------------------- grid barrier (2-level) ------------------------
__device__ __forceinline__ void gbar(unsigned* base, int blk) {
    __syncthreads();
    if (threadIdx.x == 0) {
        __threadfence();
        unsigned* rcnt = base;
        unsigned* rgen = base + 16;
        unsigned* gcnt = base + 64 + (blk >> 4) * 32;
        unsigned g0 = __hip_atomic_load(rgen, __ATOMIC_ACQUIRE, __HIP_MEMORY_SCOPE_AGENT);
        if (__hip_atomic_fetch_add(gcnt, 1u, __ATOMIC_ACQ_REL, __HIP_MEMORY_SCOPE_AGENT) == 15u) {
            __hip_atomic_store(gcnt, 0u, __ATOMIC_RELAXED, __HIP_MEMORY_SCOPE_AGENT);
            if (__hip_atomic_fetch_add(rcnt, 1u, __ATOMIC_ACQ_REL, __HIP_MEMORY_SCOPE_AGENT) == 15u) {
                __hip_atomic_store(rcnt, 0u, __ATOMIC_RELAXED, __HIP_MEMORY_SCOPE_AGENT);
                __hip_atomic_fetch_add(rgen, 1u, __ATOMIC_RELEASE, __HIP_MEMORY_SCOPE_AGENT);
            }
        }
        while (__hip_atomic_load(rgen, __ATOMIC_RELAXED, __HIP_MEMORY_SCOPE_AGENT) == g0)
            __builtin_amdgcn_s_sleep(4);
        __threadfence();
    }
    __syncthreads();
}

// --------------------------- main pipeline ---------------------------------
__global__ void __launch_bounds__(1024, 4)
hand_pipeline(const int* __restrict__ chars, const float* __restrict__ chars_mask,
              const float* __restrict__ W_att, const float* __restrict__ b_att,
              const float* __restrict__ b0, const float* __restrict__ b1,
              const float* __restrict__ b2, const float* __restrict__ W_fc,
              const float* __restrict__ b_fc,
              const float* __restrict__ wpA, const float* __restrict__ wpB,
              const float* __restrict__ wpC, const float* __restrict__ wpD,
              float* ws, float* __restrict__ out) {
    __shared__ float smem[L_TOT];
    float* REDA  = smem + L_REDA;
    float* REDB  = smem + L_REDB;
    float* REDC  = smem + L_REDC;
    float* GATES = smem + L_GATES;
    float* WATT  = smem + L_WATT;
    float* HCOL  = smem + L_HCOL;
    float* ABK   = smem + L_ABK;
    float* KAP   = smem + L_KAP;
    float* PHI   = smem + L_PHI;
    float* MSK   = smem + L_MSK;
    int*   CHS   = (int*)(smem + L_CHS);

    const int tid = threadIdx.x;
    const int blk = blockIdx.x;
    const int b   = tid & 63;
    const int wv  = __builtin_amdgcn_readfirstlane(tid >> 6);
    unsigned* bar = (unsigned*)ws;

    // one-time preload
    for (int i = tid; i < 30 * HH; i += 1024) WATT[i] = W_att[i];
    if (blk < 64) {
        if (tid < 100) { CHS[tid] = chars[blk * UU + tid]; MSK[tid] = chars_mask[blk * UU + tid]; }
        if (tid < 16) KAP[tid] = 0.f;
    }
    __syncthreads();

    float cL = 0.f;   // tid<128: L0 cell, tid 128..255: L1 cell
    float c2 = 0.f;   // tid<128: L2 cell

    const float* WAb = wpA + (size_t)blk * (592 * 16);
    const float* WBb = wpB + (size_t)blk * (520 * 8);
    const float* WCb = wpC + (size_t)blk * (4 * 8);
    const float* WDb = wpD + (size_t)blk * (1108 * 8);
    const bool fcb = (blk >= 64 && blk < 125);
    const int o0 = (blk - 64) * 2;

    for (int s = 0; s <= TT + 1; ++s) {
        const int cur = s & 3, sl = (s - 1) & 3, sl2 = (s - 2) & 3;
        // ================= P1: L0(t=s) + L1(t=s-1) ==========================
        if (s <= TT) {
            const float* WRp = ws + OFF_WR + sl * (VV * BB);
            const float* H0p = ws + OFF_H0 + sl * (HH * BB);
            const float* H1p = ws + OFF_H1 + sl2 * (HH * BB);
            if (wv < 11) {                       // JA: shared x (w|h0), 16 rows
                float acc[16];
#pragma unroll
                for (int r = 0; r < 16; ++r) acc[r] = 0.f;
                int k0, k1;
                if (wv < 8) { k0 = wv * 56; k1 = k0 + 56; }
                else        { k0 = 448 + (wv - 8) * 48; k1 = k0 + 48; }
                int e = min(k1, 80);
                if (k0 < e) run16(acc, WAb, WRp, k0, e, b);
                int l = max(k0, 80);
                if (l < k1) run16(acc, WAb, H0p - 80 * 64, l, k1, b);
#pragma unroll
                for (int r = 0; r < 16; ++r) REDA[wv * 1024 + r * 64 + b] = acc[r];
            } else {                             // JB: L1 strokes+h1prev, 8 rows
                float acc[8];
#pragma unroll
                for (int r = 0; r < 8; ++r) acc[r] = 0.f;
                int k0 = (wv - 11) * 104, k1 = k0 + 104;
                if (s >= 1) {
                    if (k0 == 0) {
                        const float* STs1 = ws + OFF_ST + (s - 1) * 192;
#pragma unroll
                        for (int kk = 0; kk < 3; ++kk) {
                            const float x = STs1[kk * 64 + b];
                            const float4 w0 = *(const float4*)(WBb + kk * 8);
                            const float4 w1 = *(const float4*)(WBb + kk * 8 + 4);
                            acc[0] = fmaf(x, w0.x, acc[0]); acc[1] = fmaf(x, w0.y, acc[1]);
                            acc[2] = fmaf(x, w0.z, acc[2]); acc[3] = fmaf(x, w0.w, acc[3]);
                            acc[4] = fmaf(x, w1.x, acc[4]); acc[5] = fmaf(x, w1.y, acc[5]);
                            acc[6] = fmaf(x, w1.z, acc[6]); acc[7] = fmaf(x, w1.w, acc[7]);
                        }
                    }
                    run8(acc, WBb, H1p - 4 * 64, max(k0, 4), min(k1, 516), b);
                }
#pragma unroll
                for (int r = 0; r < 8; ++r) REDB[(wv - 11) * 512 + r * 64 + b] = acc[r];
                if (wv == 15) {                  // JC: L0 strokes, 8 rows
                    float ac2[8];
#pragma unroll
                    for (int r = 0; r < 8; ++r) ac2[r] = 0.f;
                    if (s < TT) {
                        const float* STs = ws + OFF_ST + s * 192;
#pragma unroll
                        for (int kk = 0; kk < 3; ++kk) {
                            const float x = STs[kk * 64 + b];
                            const float4 w0 = *(const float4*)(WCb + kk * 8);
                            const float4 w1 = *(const float4*)(WCb + kk * 8 + 4);
                            ac2[0] = fmaf(x, w0.x, ac2[0]); ac2[1] = fmaf(x, w0.y, ac2[1]);
                            ac2[2] = fmaf(x, w0.z, ac2[2]); ac2[3] = fmaf(x, w0.w, ac2[3]);
                            ac2[4] = fmaf(x, w1.x, ac2[4]); ac2[5] = fmaf(x, w1.y, ac2[5]);
                            ac2[6] = fmaf(x, w1.z, ac2[6]); ac2[7] = fmaf(x, w1.w, ac2[7]);
                        }
                    }
#pragma unroll
                    for (int r = 0; r < 8; ++r) REDC[r * 64 + b] = ac2[r];
                }
            }
            __syncthreads();
            {   // reduce: wave wv handles global row wv
                float sum;
                if (wv < 8) {
                    sum = REDC[wv * 64 + b];
#pragma unroll
                    for (int w = 0; w < 11; ++w) sum += REDA[w * 1024 + wv * 64 + b];
                    sum += b0[(wv & 3) * HH + blk * 2 + (wv >> 2)];
                } else {
                    const int rr = wv - 8;
                    sum = 0.f;
#pragma unroll
                    for (int w = 0; w < 11; ++w) sum += REDA[w * 1024 + (8 + rr) * 64 + b];
#pragma unroll
                    for (int v = 0; v < 5; ++v) sum += REDB[v * 512 + rr * 64 + b];
                    sum += b1[(rr & 3) * HH + blk * 2 + (rr >> 2)];
                }
                GATES[wv * 64 + b] = sum;
            }
            __syncthreads();
            if (tid < 256) {   // cell updates: L0 (tid<128), L1 (tid 128..255)
                const int lay = tid >> 7, hu = (tid >> 6) & 1, bb = tid & 63;
                const bool act = (lay == 0) ? (s < TT) : (s >= 1);
                if (act) {
                    const int r0 = lay * 8 + hu * 4;
                    const float gi = GATES[(r0 + 0) * 64 + bb];
                    const float gf = GATES[(r0 + 1) * 64 + bb];
                    const float gg = GATES[(r0 + 2) * 64 + bb];
                    const float go = GATES[(r0 + 3) * 64 + bb];
                    cL = sigmf(gf) * cL + sigmf(gi) * tanhf_(gg);
                    const float h = sigmf(go) * tanhf_(cL);
                    if (lay == 0) ws[OFF_H0 + cur * (HH * BB) + (blk * 2 + hu) * 64 + bb] = h;
                    else          ws[OFF_H1 + sl  * (HH * BB) + (blk * 2 + hu) * 64 + bb] = h;
                }
            }
        }
        gbar(bar, blk);

        // ================= P2: L2(t=s-1) + FC(t=s-2) + ATT(t=s) ============
        {
            if (s >= 1 && s <= TT) {             // JD: L2, 8 rows
                const float* WRp = ws + OFF_WR + sl * (VV * BB);
                const float* H1p = ws + OFF_H1 + sl * (HH * BB);
                const float* H2p = ws + OFF_H2 + sl2 * (HH * BB);
                float acc[8];
#pragma unroll
                for (int r = 0; r < 8; ++r) acc[r] = 0.f;
                const int k0 = (wv < 15) ? wv * 72 : 1080;
                const int k1 = (wv < 15) ? k0 + 72 : 1108;
                if (k0 == 0) {
                    const float* STs1 = ws + OFF_ST + (s - 1) * 192;
#pragma unroll
                    for (int kk = 0; kk < 3; ++kk) {
                        const float x = STs1[kk * 64 + b];
                        const float4 w0 = *(const float4*)(WDb + kk * 8);
                        const float4 w1 = *(const float4*)(WDb + kk * 8 + 4);
                        acc[0] = fmaf(x, w0.x, acc[0]); acc[1] = fmaf(x, w0.y, acc[1]);
                        acc[2] = fmaf(x, w0.z, acc[2]); acc[3] = fmaf(x, w0.w, acc[3]);
                        acc[4] = fmaf(x, w1.x, acc[4]); acc[5] = fmaf(x, w1.y, acc[5]);
                        acc[6] = fmaf(x, w1.z, acc[6]); acc[7] = fmaf(x, w1.w, acc[7]);
                    }
                }
                int a_ = max(k0, 4), e_ = min(k1, 84);
                if (a_ < e_) run8(acc, WDb, WRp - 4 * 64, a_, e_, b);
                a_ = max(k0, 84); e_ = min(k1, 596);
                if (a_ < e_) run8(acc, WDb, H1p - 84 * 64, a_, e_, b);
                a_ = max(k0, 596);
                if (a_ < k1) run8(acc, WDb, H2p - 596 * 64, a_, k1, b);
#pragma unroll
                for (int r = 0; r < 8; ++r) REDA[wv * 512 + r * 64 + b] = acc[r];
            }
            if (fcb && s >= 2) {                 // FC partials, 2 outputs
                const float* H0f = ws + OFF_H0 + sl2 * (HH * BB);
                const float* H1f = ws + OFF_H1 + sl2 * (HH * BB);
                const float* H2f = ws + OFF_H2 + sl2 * (HH * BB);
                const float* w0p = W_fc + (size_t)o0 * 1536;
                // OOB FIX: for blk=124 (o0=120), o0+1==121 is out of range ->
                // alias w1p to w0p (in-bounds); its result is discarded below.
                const float* w1p = w0p + (((o0 + 1) < NOUT) ? 1536 : 0);
                float f0 = 0.f, f1 = 0.f;
                int ka = wv * 96;
                const int kend = ka + 96;
                while (ka < kend) {
                    const float* Xb; int se;
                    if (ka < 512)       { Xb = H0f;            se = 512; }
                    else if (ka < 1024) { Xb = H1f - 512 * 64; se = 1024; }
                    else                { Xb = H2f - 1024 * 64; se = 1536; }
                    const int e = min(kend, se);
#pragma unroll 4
                    for (int k = ka; k < e; ++k) {
                        const float x = Xb[k * 64 + b];
                        f0 = fmaf(x, w0p[k], f0);
                        f1 = fmaf(x, w1p[k], f1);
                    }
                    ka = e;
                }
                REDB[wv * 128 + b] = f0;
                REDB[wv * 128 + 64 + b] = f1;
            }
            __syncthreads();
            if (wv < 8) {                        // L2 gate reduce
                float sum = 0.f;
#pragma unroll
                for (int w = 0; w < 16; ++w) sum += REDA[w * 512 + wv * 64 + b];
                sum += b2[(wv & 3) * HH + blk * 2 + (wv >> 2)];
                GATES[wv * 64 + b] = sum;
            } else if (fcb && s >= 2 && wv < 10) {   // FC reduce + store
                const int ol = wv - 8, o = o0 + ol;
                if (o < NOUT) {
                    float sum = b_fc[o];
#pragma unroll
                    for (int w = 0; w < 16; ++w) sum += REDB[w * 128 + ol * 64 + b];
                    out[((size_t)b * TT + (s - 2)) * NOUT + o] = sum;
                }
            }
            __syncthreads();
            if (tid < 128 && s >= 1 && s <= TT) {    // L2 cell
                const int hu = tid >> 6, bb = tid & 63;
                const float gi = GATES[(hu * 4 + 0) * 64 + bb];
                const float gf = GATES[(hu * 4 + 1) * 64 + bb];
                const float gg = GATES[(hu * 4 + 2) * 64 + bb];
                const float go = GATES[(hu * 4 + 3) * 64 + bb];
                c2 = sigmf(gf) * c2 + sigmf(gi) * tanhf_(gg);
                ws[OFF_H2 + sl * (HH * BB) + (blk * 2 + hu) * 64 + bb] = sigmf(go) * tanhf_(c2);
            }
            if (blk < 64 && s < TT) {                // ATT (block = batch)
                __syncthreads();
                if (tid < 512) HCOL[tid] = ws[OFF_H0 + cur * (HH * BB) + tid * 64 + blk];
                __syncthreads();
                if (tid < 480) {
                    const int a = tid >> 4, p = tid & 15;
                    float d = 0.f;
#pragma unroll 8
                    for (int n = 0; n < 32; ++n)
                        d = fmaf(HCOL[p * 32 + n], WATT[a * 512 + p * 32 + n], d);
                    d += __shfl_down(d, 8, 16);
                    d += __shfl_down(d, 4, 16);
                    d += __shfl_down(d, 2, 16);
                    d += __shfl_down(d, 1, 16);
                    if (p == 0) ABK[a] = __expf(d + b_att[a]);
                }
                __syncthreads();
                if (tid < 10) { const float kv = ABK[20 + tid] * 0.05f + KAP[tid]; KAP[tid] = kv; }
                __syncthreads();
                if (tid < 100) {
                    const float u = (float)tid;
                    float ph = 0.f;
#pragma unroll
                    for (int ka = 0; ka < 10; ++ka) {
                        const float d = KAP[ka] - u;
                        ph += ABK[ka] * __expf(-ABK[10 + ka] * d * d);
                    }
                    PHI[tid] = ph * MSK[tid];
                }
                __syncthreads();
                if (tid < 80) {
                    float wvv = 0.f;
                    for (int u2 = 0; u2 < 100; ++u2)
                        if (CHS[u2] == tid) wvv += PHI[u2] * MSK[u2];
                    ws[OFF_WR + cur * (VV * BB) + tid * 64 + blk] = wvv;
                }
            }
        }
        gbar(bar, blk);
    }
}

// ------------------------ output postprocessing ----------------------------
__global__ void postproc_kernel(float* __restrict__ out) {
    int row  = blockIdx.x * 8 + (threadIdx.x >> 5);
    int lane = threadIdx.x & 31;
    float* r = out + (size_t)row * NOUT;
    float pv = (lane < 20) ? r[80 + lane] : -1e30f;
    float m = pv;
#pragma unroll
    for (int off = 16; off; off >>= 1) m = fmaxf(m, __shfl_xor(m, off, 32));
    float e = (lane < 20) ? __expf(pv - m) : 0.f;
    float sm = e;
#pragma unroll
    for (int off = 16; off; off >>= 1) sm += __shfl_xor(sm, off, 32);
    float logZ = m + __logf(sm);
    float res[4];
    bool wr[4];
    int ps[4];
#pragma unroll
    for (int i = 0; i < 4; ++i) {
        int p = lane + 32 * i;
        ps[i] = p;
        wr[i] = (p < NOUT);
        float x = 0.f;
        if (p < 20)       x = pv - logZ;
        else if (p < 100) { if (wr[i]) x = r[p - 20]; }
        else if (p < 120) x = tanhf_(r[p]);
        else if (p == 120) x = 1.f / (1.f + __expf(r[120]));
        res[i] = x;
    }
#pragma unroll
    for (int i = 0; i < 4; ++i)
        if (wr[i]) r[ps[i]] = res[i];
}

// ------------------------------- launcher ----------------------------------
extern "C" void kernel_launch(void* const* d_in, const int* in_sizes, int n_in,
                              void* d_out, int out_size, void* d_ws, size_t ws_size,
                              hipStream_t stream) {
    const int*   chars      = (const int*)d_in[0];
    const float* chars_mask = (const float*)d_in[1];
    const float* strokes    = (const float*)d_in[2];
    const float* W_ih0 = (const float*)d_in[4];
    const float* W_hh0 = (const float*)d_in[5];
    const float* b0    = (const float*)d_in[6];
    const float* W_att = (const float*)d_in[7];
    const float* b_att = (const float*)d_in[8];
    const float* W_ih1 = (const float*)d_in[9];
    const float* W_hh1 = (const float*)d_in[10];
    const float* b1    = (const float*)d_in[11];
    const float* W_ih2 = (const float*)d_in[12];
    const float* W_hh2 = (const float*)d_in[13];
    const float* b2    = (const float*)d_in[14];
    const float* W_fc  = (const float*)d_in[15];
    const float* b_fc  = (const float*)d_in[16];
    float* ws  = (float*)d_ws;
    float* out = (float*)d_out;

    const int nz = 1024 + 3 * 4 * HH * BB + 4 * VV * BB;
    prep_zero<<<(nz + 255) / 256, 256, 0, stream>>>(ws);
    prep_strokesT<<<(TT * 3 * BB + 255) / 256, 256, 0, stream>>>(strokes, ws);
    prep_wa<<<(256 * 592 * 16 + 255) / 256, 256, 0, stream>>>(W_ih0, W_hh0, W_ih1, ws + OFF_WA);
    prep_wb<<<(256 * 520 * 8 + 255) / 256, 256, 0, stream>>>(W_ih1, W_hh1, ws + OFF_WB);
    prep_wc<<<(256 * 4 * 8 + 255) / 256, 256, 0, stream>>>(W_ih0, ws + OFF_WC);
    prep_wd<<<(256 * 1108 * 8 + 255) / 256, 256, 0, stream>>>(W_ih2, W_hh2, ws + OFF_WD);

    hand_pipeline<<<256, 1024, 0, stream>>>(chars, chars_mask, W_att, b_att,
                                            b0, b1, b2, W_fc, b_fc,
                                            ws + OFF_WA, ws + OFF_WB, ws + OFF_WC, ws + OFF_WD,
                                            ws, out);
    postproc_kernel<<<(BB * TT) / 8, 256, 0, stream>>>(out);
}

// Round 4
// 49923.453 us; speedup vs baseline: 5.8846x; 1.3970x over previous
//
#include <hip/hip_runtime.h>

// ---------------------------------------------------------------------------
// HandwritingSynthesisNetwork on MI355X — round 4.
// Persistent kernel, 256 blocks x 1024 threads. Two grid-barrier phases/step:
//   P1(s): L0 gates (t=s) + L1 gates (t=s-1)
//   P2(s): L2 gates (t=s-1) + FC (t=s-2, 1 output/block over 121 blocks) + ATT (t=s)
// Round-4 changes (fix exposed global-load latency, VALUBusy 10%):
//  - ALL gate/FC weights live in LDS (filled once; constant over 800 steps).
//    Inner loops read weights as wave-uniform ds_read broadcasts.
//  - x panels read from global rings with explicit depth-4 register prefetch.
//  - Combined rings XA=[w|h0], XB=[w|h1] (ATT dup-writes w) -> contiguous
//    GEMV panels; strokes cols folded into the reduce step (WST in LDS).
//  - FC: 121 blocks x 1 output (halves fcb straggler tail).
//  - No packed-weight prep kernels; ws only holds rings/strokes (2.4 MB).
// ---------------------------------------------------------------------------

#define TT   800
#define BB   64
#define UU   100
#define VV   80
#define HH   512
#define NOUT 121

#define XASZ (592 * 64)
#define H2SZ (512 * 64)

// ---- ws float offsets ----
#define WS_BAR 0
#define WS_ST  1024                       // [800][3][64]
#define WS_XA  (WS_ST + TT * 3 * 64)      // [4][592][64]: rows 0..79 w, 80..591 h0
#define WS_XB  (WS_XA + 4 * XASZ)         // [4][592][64]: rows 0..79 w, 80..591 h1
#define WS_H2  (WS_XB + 4 * XASZ)         // [4][512][64]
#define WS_END (WS_H2 + 4 * H2SZ + 2048)  // +guard for prefetch overruns

// ---- LDS float offsets (total 38144 fl = 152,576 B) ----
#define L_WA   0        // [8][76][16] = 9728   (JA: L0+L1 over [w|h0], pad i>=74 zero)
#define L_WB   9728     // [8][64][8]  = 4096   (JB: Whh1)
#define L_WD1  13824    // [8][76][8]  = 4864   (JD: L2 over [w|h1], pad i>=74 zero)
#define L_WD2  18688    // [8][64][8]  = 4096   (JD: Whh2)
#define L_FC   22784    // [1536]      = 1536   (this block's single FC row)
#define L_WST  24320    // [3][3][8]   = 72 used, 128 alloc (strokes cols)
#define L_REDA 24448    // 8192: P1 JA partials [8][16][64]; P2 JD [16][8][64]
#define L_REDB 32640    // 4096: P1 JB partials [8][8][64]; P2 FC [16][64]; +2048 = HCOL alias
#define L_GATE 36736    // [16][64]
#define L_KAP  37760    // 16
#define L_ABK  37776    // 32
#define L_PHI  37808    // 112
#define L_MSK  37920    // 112
#define L_CHS  38032    // 112 (ints)
#define L_TOT  38144

__device__ __forceinline__ float sigmf(float x) { return 1.f / (1.f + __expf(-x)); }
__device__ __forceinline__ float tanhf_(float x) { return 1.f - 2.f / (1.f + __expf(2.f * x)); }

// NR-row GEMV slice: weights from LDS (wave-uniform broadcast), x from global
// with depth-4 register prefetch. NK must be a multiple of 4. x reads may run
// 4 rows past the panel (ws has guard space; pad weights are zero).
template<int NR, int NK>
__device__ __forceinline__ void gemv_pf(float* acc, const float* __restrict__ Wl,
                                        const float* __restrict__ Xg, int b) {
    const float* Xp = Xg + b;
    float xr[4];
#pragma unroll
    for (int u = 0; u < 4; ++u) xr[u] = Xp[u * 64];
#pragma unroll 1
    for (int k = 0; k < NK; k += 4) {
        float xn[4];
#pragma unroll
        for (int u = 0; u < 4; ++u) xn[u] = Xp[(k + 4 + u) * 64];
#pragma unroll
        for (int u = 0; u < 4; ++u) {
            const float x = xr[u];
            const float4* wp = (const float4*)(Wl + (k + u) * NR);
#pragma unroll
            for (int q = 0; q < NR / 4; ++q) {
                const float4 w = wp[q];
                acc[q * 4 + 0] = fmaf(x, w.x, acc[q * 4 + 0]);
                acc[q * 4 + 1] = fmaf(x, w.y, acc[q * 4 + 1]);
                acc[q * 4 + 2] = fmaf(x, w.z, acc[q * 4 + 2]);
                acc[q * 4 + 3] = fmaf(x, w.w, acc[q * 4 + 3]);
            }
        }
#pragma unroll
        for (int u = 0; u < 4; ++u) xr[u] = xn[u];
    }
}

// FC 1-row segment, dynamic bounds (k0,k1 multiples of 4), depth-4 prefetch.
__device__ __forceinline__ void fc_seg(float& f, const float* __restrict__ Wl,
                                       const float* __restrict__ Xlane, int k0, int k1) {
    float xr[4];
#pragma unroll
    for (int u = 0; u < 4; ++u) xr[u] = Xlane[(k0 + u) * 64];
#pragma unroll 1
    for (int k = k0; k < k1; k += 4) {
        float xn[4];
#pragma unroll
        for (int u = 0; u < 4; ++u) xn[u] = Xlane[(k + 4 + u) * 64];
#pragma unroll
        for (int u = 0; u < 4; ++u) f = fmaf(xr[u], Wl[k + u], f);
#pragma unroll
        for (int u = 0; u < 4; ++u) xr[u] = xn[u];
    }
}

// --------------------------- prep kernels ----------------------------------
__global__ void prep_zero4(float4* __restrict__ ws4) {
    int i = blockIdx.x * blockDim.x + threadIdx.x;
    if (i < WS_END / 4) ws4[i] = make_float4(0.f, 0.f, 0.f, 0.f);
}

__global__ void prep_strokesT(const float* __restrict__ strokes, float* __restrict__ ws) {
    int idx = blockIdx.x * blockDim.x + threadIdx.x;
    if (idx >= TT * 3 * BB) return;
    int b = idx & 63;
    int tk = idx >> 6;
    int k = tk % 3, t = tk / 3;
    ws[WS_ST + idx] = strokes[((size_t)b * TT + t) * 3 + k];
}

// --------------------------- grid barrier (2-level) ------------------------
__device__ __forceinline__ void gbar(unsigned* base, int blk) {
    __syncthreads();
    if (threadIdx.x == 0) {
        __threadfence();
        unsigned* rcnt = base;
        unsigned* rgen = base + 16;
        unsigned* gcnt = base + 64 + (blk >> 4) * 32;
        unsigned g0 = __hip_atomic_load(rgen, __ATOMIC_ACQUIRE, __HIP_MEMORY_SCOPE_AGENT);
        if (__hip_atomic_fetch_add(gcnt, 1u, __ATOMIC_ACQ_REL, __HIP_MEMORY_SCOPE_AGENT) == 15u) {
            __hip_atomic_store(gcnt, 0u, __ATOMIC_RELAXED, __HIP_MEMORY_SCOPE_AGENT);
            if (__hip_atomic_fetch_add(rcnt, 1u, __ATOMIC_ACQ_REL, __HIP_MEMORY_SCOPE_AGENT) == 15u) {
                __hip_atomic_store(rcnt, 0u, __ATOMIC_RELAXED, __HIP_MEMORY_SCOPE_AGENT);
                __hip_atomic_fetch_add(rgen, 1u, __ATOMIC_RELEASE, __HIP_MEMORY_SCOPE_AGENT);
            }
        }
        while (__hip_atomic_load(rgen, __ATOMIC_RELAXED, __HIP_MEMORY_SCOPE_AGENT) == g0)
            __builtin_amdgcn_s_sleep(2);
        __threadfence();
    }
    __syncthreads();
}

// --------------------------- main pipeline ---------------------------------
__global__ void __launch_bounds__(1024, 4)
hand_pipeline(const int* __restrict__ chars, const float* __restrict__ chars_mask,
              const float* __restrict__ W_att, const float* __restrict__ b_att,
              const float* __restrict__ Wih0, const float* __restrict__ Whh0,
              const float* __restrict__ b0,
              const float* __restrict__ Wih1, const float* __restrict__ Whh1,
              const float* __restrict__ b1,
              const float* __restrict__ Wih2, const float* __restrict__ Whh2,
              const float* __restrict__ b2,
              const float* __restrict__ W_fc, const float* __restrict__ b_fc,
              float* ws, float* __restrict__ out) {
    __shared__ float smem[L_TOT];
    float* REDA  = smem + L_REDA;
    float* REDB  = smem + L_REDB;
    float* GATES = smem + L_GATE;
    float* HCOL  = smem + L_REDB + 2048;   // transient, P2 only
    float* KAP   = smem + L_KAP;
    float* ABK   = smem + L_ABK;
    float* PHI   = smem + L_PHI;
    float* MSK   = smem + L_MSK;
    int*   CHS   = (int*)(smem + L_CHS);

    const int tid = threadIdx.x;
    const int blk = blockIdx.x;
    const int b   = tid & 63;
    const int wv  = __builtin_amdgcn_readfirstlane(tid >> 6);
    unsigned* bar = (unsigned*)ws;
    const bool fcb = (blk >= 64 && blk < 64 + NOUT);

    // ---- one-time LDS weight fill (strided gather from original arrays) ----
    for (int idx = tid; idx < L_REDA; idx += 1024) {
        float v = 0.f;
        if (idx < L_WB) {                       // LWA [w][76][16]: k=74w+i of [w|h0]
            int w = idx / 1216, rem = idx - w * 1216;
            int i = rem >> 4, c = rem & 15;
            int k = 74 * w + i;
            int hu = (c >> 2) & 1, g = c & 3;
            int grow = g * HH + blk * 2 + hu;
            if (i < 74) {
                if (c < 8) v = (k < 80) ? Wih0[grow * 83 + 3 + k]
                                        : Whh0[(size_t)grow * 512 + (k - 80)];
                else       v = Wih1[(size_t)grow * 595 + 3 + k];   // w|h0 cols unify
            }
        } else if (idx < L_WD1) {               // LWB [v][64][8]: Whh1
            int j2 = idx - L_WB;
            int vv = j2 >> 9, rem = j2 & 511;
            int i = rem >> 3, c = rem & 7;
            int hu = c >> 2, g = c & 3;
            int grow = g * HH + blk * 2 + hu;
            v = Whh1[(size_t)grow * 512 + vv * 64 + i];
        } else if (idx < L_WD2) {               // LWD1 [w][76][8]: L2 over [w|h1]
            int j3 = idx - L_WD1;
            int w = j3 / 608, rem = j3 - w * 608;
            int i = rem >> 3, c = rem & 7;
            int k = 74 * w + i;
            int hu = c >> 2, g = c & 3;
            int grow = g * HH + blk * 2 + hu;
            if (i < 74) v = Wih2[(size_t)grow * 595 + 3 + k];
        } else if (idx < L_FC) {                // LWD2 [v][64][8]: Whh2
            int j4 = idx - L_WD2;
            int vv = j4 >> 9, rem = j4 & 511;
            int i = rem >> 3, c = rem & 7;
            int hu = c >> 2, g = c & 3;
            int grow = g * HH + blk * 2 + hu;
            v = Whh2[(size_t)grow * 512 + vv * 64 + i];
        } else if (idx < L_WST) {               // LFC [1536]: this block's FC row
            int k = idx - L_FC;
            if (fcb) v = W_fc[(size_t)(blk - 64) * 1536 + k];
        } else {                                // LWST [lay][3][8]: strokes cols
            int j6 = idx - L_WST;
            if (j6 < 72) {
                int lay = j6 / 24, rem = j6 - lay * 24;
                int kk = rem >> 3, c = rem & 7;
                int hu = c >> 2, g = c & 3;
                int grow = g * HH + blk * 2 + hu;
                v = (lay == 0) ? Wih0[grow * 83 + kk]
                  : (lay == 1) ? Wih1[(size_t)grow * 595 + kk]
                               : Wih2[(size_t)grow * 595 + kk];
            }
        }
        smem[idx] = v;
    }
    if (blk < 64) {
        if (tid < 100) { CHS[tid] = chars[blk * UU + tid]; MSK[tid] = chars_mask[blk * UU + tid]; }
        if (tid < 16) KAP[tid] = 0.f;
    }
    __syncthreads();

    float cL = 0.f;   // tid<128: L0 cell; tid 128..255: L1 cell
    float c2 = 0.f;   // tid<128: L2 cell

    for (int s = 0; s <= TT + 1; ++s) {
        const int cur = s & 3, sl = (s - 1) & 3, sl2 = (s - 2) & 3;

        // ================= P1: L0(t=s) + L1(t=s-1) ==========================
        if (s <= TT) {
            if (wv < 8) {          // JA: 16 rows over XA[sl] = [w|h0]_{s-1}
                float acc[16];
#pragma unroll
                for (int r = 0; r < 16; ++r) acc[r] = 0.f;
                gemv_pf<16, 76>(acc, smem + L_WA + wv * 1216,
                                ws + WS_XA + sl * XASZ + 74 * wv * 64, b);
#pragma unroll
                for (int r = 0; r < 16; ++r) REDA[wv * 1024 + r * 64 + b] = acc[r];
            } else {               // JB: 8 rows (L1) over h1_{s-2}
                const int v = wv - 8;
                float acc[8];
#pragma unroll
                for (int r = 0; r < 8; ++r) acc[r] = 0.f;
                gemv_pf<8, 64>(acc, smem + L_WB + v * 512,
                               ws + WS_XB + sl2 * XASZ + (80 + 64 * v) * 64, b);
#pragma unroll
                for (int r = 0; r < 8; ++r) REDB[v * 512 + r * 64 + b] = acc[r];
            }
            __syncthreads();
            {   // reduce: wave wv owns gate row wv; fold strokes + bias here
                const int r = wv, rl = r & 7, hu = rl >> 2, g = rl & 3;
                const int bi = g * HH + blk * 2 + hu;
                const int lay = r >> 3;
                float sum;
                int ts;
                if (r < 8) { sum = b0[bi]; ts = (s < TT) ? s : TT - 1; }
                else       { sum = b1[bi]; ts = (s >= 1) ? s - 1 : 0; }
                const float* st = ws + WS_ST + ts * 192 + b;
#pragma unroll
                for (int kk = 0; kk < 3; ++kk)
                    sum = fmaf(st[kk * 64], smem[L_WST + lay * 24 + kk * 8 + rl], sum);
#pragma unroll
                for (int w = 0; w < 8; ++w) sum += REDA[w * 1024 + r * 64 + b];
                if (r >= 8) {
#pragma unroll
                    for (int v = 0; v < 8; ++v) sum += REDB[v * 512 + rl * 64 + b];
                }
                GATES[r * 64 + b] = sum;
            }
            __syncthreads();
            if (tid < 256) {   // cell updates: L0 (tid<128), L1 (tid 128..255)
                const int lay = tid >> 7, hu = (tid >> 6) & 1, bb = tid & 63;
                const bool act = (lay == 0) ? (s < TT) : (s >= 1);
                if (act) {
                    const int r0 = lay * 8 + hu * 4;
                    const float gi = GATES[(r0 + 0) * 64 + bb];
                    const float gf = GATES[(r0 + 1) * 64 + bb];
                    const float gg = GATES[(r0 + 2) * 64 + bb];
                    const float go = GATES[(r0 + 3) * 64 + bb];
                    cL = sigmf(gf) * cL + sigmf(gi) * tanhf_(gg);
                    const float h = sigmf(go) * tanhf_(cL);
                    const int row = 80 + blk * 2 + hu;
                    if (lay == 0) ws[WS_XA + cur * XASZ + row * 64 + bb] = h;
                    else          ws[WS_XB + sl  * XASZ + row * 64 + bb] = h;
                }
            }
        }
        gbar(bar, blk);

        // ================= P2: L2(t=s-1) + FC(t=s-2) + ATT(t=s) ============
        {
            if (s <= TT) {         // JD: 8 rows over XB[sl]=[w|h1]_{s-1} + h2_{s-2}
                float acc[8];
#pragma unroll
                for (int r = 0; r < 8; ++r) acc[r] = 0.f;
                if (wv < 8) {
                    gemv_pf<8, 76>(acc, smem + L_WD1 + wv * 608,
                                   ws + WS_XB + sl * XASZ + 74 * wv * 64, b);
                } else {
                    const int v = wv - 8;
                    gemv_pf<8, 64>(acc, smem + L_WD2 + v * 512,
                                   ws + WS_H2 + sl2 * H2SZ + 64 * v * 64, b);
                }
#pragma unroll
                for (int r = 0; r < 8; ++r) REDA[wv * 512 + r * 64 + b] = acc[r];
            }
            if (fcb && s >= 2) {   // FC: 1 output/block, wave k-slice 96
                float f = 0.f;
                const int ks = 96 * wv, ke = ks + 96;
                const float* X0 = ws + WS_XA + sl2 * XASZ + 80 * 64 + b;
                const float* X1 = ws + WS_XB + sl2 * XASZ + 80 * 64 + b - 512 * 64;
                const float* X2 = ws + WS_H2 + sl2 * H2SZ + b - 1024 * 64;
                int a0_ = ks, e0 = min(ke, 512);
                if (a0_ < e0) fc_seg(f, smem + L_FC, X0, a0_, e0);
                a0_ = max(ks, 512); e0 = min(ke, 1024);
                if (a0_ < e0) fc_seg(f, smem + L_FC, X1, a0_, e0);
                a0_ = max(ks, 1024);
                if (a0_ < ke) fc_seg(f, smem + L_FC, X2, a0_, ke);
                REDB[wv * 64 + b] = f;
            }
            __syncthreads();
            if (wv < 8) {          // L2 gate reduce (+strokes t=s-1, +b2)
                const int rl = wv, hu = rl >> 2, g = rl & 3;
                float sum = b2[g * HH + blk * 2 + hu];
                int ts = (s >= 1) ? s - 1 : 0;
                if (ts > TT - 1) ts = TT - 1;
                const float* st = ws + WS_ST + ts * 192 + b;
#pragma unroll
                for (int kk = 0; kk < 3; ++kk)
                    sum = fmaf(st[kk * 64], smem[L_WST + 2 * 24 + kk * 8 + rl], sum);
#pragma unroll
                for (int w = 0; w < 16; ++w) sum += REDA[w * 512 + rl * 64 + b];
                GATES[rl * 64 + b] = sum;
            } else if (wv == 8 && fcb && s >= 2) {   // FC reduce + store
                float sum = b_fc[blk - 64];
#pragma unroll
                for (int w = 0; w < 16; ++w) sum += REDB[w * 64 + b];
                out[((size_t)b * TT + (s - 2)) * NOUT + (blk - 64)] = sum;
            }
            __syncthreads();
            if (tid < 128 && s >= 1 && s <= TT) {    // L2 cell -> H2[sl]
                const int hu = tid >> 6, bb = tid & 63;
                const float gi = GATES[(hu * 4 + 0) * 64 + bb];
                const float gf = GATES[(hu * 4 + 1) * 64 + bb];
                const float gg = GATES[(hu * 4 + 2) * 64 + bb];
                const float go = GATES[(hu * 4 + 3) * 64 + bb];
                c2 = sigmf(gf) * c2 + sigmf(gi) * tanhf_(gg);
                ws[WS_H2 + sl * H2SZ + (blk * 2 + hu) * 64 + bb] = sigmf(go) * tanhf_(c2);
            }
            if (blk < 64 && s < TT) {                // ATT (block = batch)
                __syncthreads();
                if (tid < 512) HCOL[tid] = ws[WS_XA + cur * XASZ + (80 + tid) * 64 + blk];
                __syncthreads();
                if (tid < 480) {
                    const int a = tid >> 4, p = tid & 15;
                    const float4* wa = (const float4*)(W_att + a * HH + p * 32);
                    const float* hc = HCOL + p * 32;
                    float d = 0.f;
#pragma unroll
                    for (int n = 0; n < 8; ++n) {
                        const float4 w4 = wa[n];
                        d = fmaf(hc[n * 4 + 0], w4.x, fmaf(hc[n * 4 + 1], w4.y,
                            fmaf(hc[n * 4 + 2], w4.z, fmaf(hc[n * 4 + 3], w4.w, d))));
                    }
                    d += __shfl_down(d, 8, 16);
                    d += __shfl_down(d, 4, 16);
                    d += __shfl_down(d, 2, 16);
                    d += __shfl_down(d, 1, 16);
                    if (p == 0) ABK[a] = __expf(d + b_att[a]);
                }
                __syncthreads();
                if (tid < 10) { const float kv = ABK[20 + tid] * 0.05f + KAP[tid]; KAP[tid] = kv; }
                __syncthreads();
                if (tid < 100) {
                    const float u = (float)tid;
                    float ph = 0.f;
#pragma unroll
                    for (int ka = 0; ka < 10; ++ka) {
                        const float d = KAP[ka] - u;
                        ph += ABK[ka] * __expf(-ABK[10 + ka] * d * d);
                    }
                    PHI[tid] = ph * MSK[tid];
                }
                __syncthreads();
                if (tid < 80) {
                    float wvv = 0.f;
                    for (int u2 = 0; u2 < 100; ++u2)
                        if (CHS[u2] == tid) wvv += PHI[u2] * MSK[u2];
                    ws[WS_XA + cur * XASZ + tid * 64 + blk] = wvv;   // for L0/L1 (JA)
                    ws[WS_XB + cur * XASZ + tid * 64 + blk] = wvv;   // for L2 (JD)
                }
            }
        }
        gbar(bar, blk);
    }
}

// ------------------------ output postprocessing ----------------------------
__global__ void postproc_kernel(float* __restrict__ out) {
    int row  = blockIdx.x * 8 + (threadIdx.x >> 5);
    int lane = threadIdx.x & 31;
    float* r = out + (size_t)row * NOUT;
    float pv = (lane < 20) ? r[80 + lane] : -1e30f;
    float m = pv;
#pragma unroll
    for (int off = 16; off; off >>= 1) m = fmaxf(m, __shfl_xor(m, off, 32));
    float e = (lane < 20) ? __expf(pv - m) : 0.f;
    float sm = e;
#pragma unroll
    for (int off = 16; off; off >>= 1) sm += __shfl_xor(sm, off, 32);
    float logZ = m + __logf(sm);
    float res[4];
    bool wr[4];
    int ps[4];
#pragma unroll
    for (int i = 0; i < 4; ++i) {
        int p = lane + 32 * i;
        ps[i] = p;
        wr[i] = (p < NOUT);
        float x = 0.f;
        if (p < 20)       x = pv - logZ;
        else if (p < 100) { if (wr[i]) x = r[p - 20]; }
        else if (p < 120) x = tanhf_(r[p]);
        else if (p == 120) x = 1.f / (1.f + __expf(r[120]));
        res[i] = x;
    }
#pragma unroll
    for (int i = 0; i < 4; ++i)
        if (wr[i]) r[ps[i]] = res[i];
}

// ------------------------------- launcher ----------------------------------
extern "C" void kernel_launch(void* const* d_in, const int* in_sizes, int n_in,
                              void* d_out, int out_size, void* d_ws, size_t ws_size,
                              hipStream_t stream) {
    const int*   chars      = (const int*)d_in[0];
    const float* chars_mask = (const float*)d_in[1];
    const float* strokes    = (const float*)d_in[2];
    const float* W_ih0 = (const float*)d_in[4];
    const float* W_hh0 = (const float*)d_in[5];
    const float* b0    = (const float*)d_in[6];
    const float* W_att = (const float*)d_in[7];
    const float* b_att = (const float*)d_in[8];
    const float* W_ih1 = (const float*)d_in[9];
    const float* W_hh1 = (const float*)d_in[10];
    const float* b1    = (const float*)d_in[11];
    const float* W_ih2 = (const float*)d_in[12];
    const float* W_hh2 = (const float*)d_in[13];
    const float* b2    = (const float*)d_in[14];
    const float* W_fc  = (const float*)d_in[15];
    const float* b_fc  = (const float*)d_in[16];
    float* ws  = (float*)d_ws;
    float* out = (float*)d_out;

    prep_zero4<<<(WS_END / 4 + 255) / 256, 256, 0, stream>>>((float4*)ws);
    prep_strokesT<<<(TT * 3 * BB + 255) / 256, 256, 0, stream>>>(strokes, ws);

    hand_pipeline<<<256, 1024, 0, stream>>>(chars, chars_mask, W_att, b_att,
                                            W_ih0, W_hh0, b0,
                                            W_ih1, W_hh1, b1,
                                            W_ih2, W_hh2, b2,
                                            W_fc, b_fc, ws, out);
    postproc_kernel<<<(BB * TT) / 8, 256, 0, stream>>>(out);
}

// Round 5
// 40017.722 us; speedup vs baseline: 7.3412x; 1.2475x over previous
//
#include <hip/hip_runtime.h>

// ---------------------------------------------------------------------------
// HandwritingSynthesisNetwork on MI355X — round 5.
// Persistent kernel, 256 blocks x 1024 threads, 2 grid-barrier phases/step:
//   P1(s): L0 gates (t=s) + L1 gates (t=s-1)
//   P2(s): L2 gates (t=s-1) + FC (t=s-2, 16 blocks x 8 outs) + ATT (t=s)
// Round-5 changes (kill per-barrier L2 writeback/invalidate):
//  - NO __threadfence. Cross-block data (rings) moved with per-access
//    device-coherent ops: relaxed agent-scope atomic load/store
//    (global_load/store_dword sc0 sc1). Weights/strokes/W_att/FC-table stay
//    ordinary cached loads and remain L2-resident across steps.
//  - Barrier: s_waitcnt vmcnt(0) + relaxed 2-level atomics (each wave's
//    __syncthreads already drains its own write-through stores).
//  - FC: 16 blocks x 8 outputs, wave = 192-k-slice x 4 outputs, weights from
//    pre-transposed WFCT[k][128] in ws (cached). Ring traffic 47.5->6.3 MB/step.
//  - gemv x prefetch depth 8 (sc1 loads always L3-latency).
// ---------------------------------------------------------------------------

#define TT   800
#define BB   64
#define UU   100
#define VV   80
#define HH   512
#define NOUT 121

#define XASZ (592 * 64)
#define H2SZ (512 * 64)

// ---- ws float offsets ----
#define WS_ST   1024                        // [800][3][64]
#define WS_XA   (WS_ST + TT * 3 * 64)       // [4][592][64]: 0..79 w, 80..591 h0
#define WS_XB   (WS_XA + 4 * XASZ)          // [4][592][64]: 0..79 w, 80..591 h1
#define WS_H2   (WS_XB + 4 * XASZ)          // [4][512][64]
#define WS_FCT  (WS_H2 + 4 * H2SZ + 2048)   // [1536][128] transposed W_fc (+guard before)
#define WS_END  (WS_FCT + 1536 * 128)

// ---- LDS float offsets (36608 fl = 146,432 B) ----
#define L_WA   0        // [8][76][16] = 9728
#define L_WB   9728     // [8][64][8]  = 4096
#define L_WD1  13824    // [8][76][8]  = 4864
#define L_WD2  18688    // [8][64][8]  = 4096
#define L_WST  22784    // [3][3][8]   = 72 used, 128 alloc
#define L_REDA 22912    // 8192: P1 JA [8][16][64]; P2 JD [16][8][64]; HCOL alias
#define L_REDB 31104    // 4096: P1 JB [8][8][64]; P2 FC [16][4][64]
#define L_GATE 35200    // [16][64]
#define L_KAP  36224    // 16
#define L_ABK  36240    // 32
#define L_PHI  36272    // 112
#define L_MSK  36384    // 112
#define L_CHS  36496    // 112 (ints)
#define L_TOT  36608

__device__ __forceinline__ float sigmf(float x) { return 1.f / (1.f + __expf(-x)); }
__device__ __forceinline__ float tanhf_(float x) { return 1.f - 2.f / (1.f + __expf(2.f * x)); }

// device-coherent (agent-scope, relaxed) load/store: sc0 sc1, no cache fences
__device__ __forceinline__ float cload(const float* p) {
    return __uint_as_float(__hip_atomic_load((unsigned int*)p, __ATOMIC_RELAXED,
                                             __HIP_MEMORY_SCOPE_AGENT));
}
__device__ __forceinline__ void cstore(float* p, float v) {
    __hip_atomic_store((unsigned int*)p, __float_as_uint(v), __ATOMIC_RELAXED,
                       __HIP_MEMORY_SCOPE_AGENT);
}

// NR-row GEMV slice: weights LDS (wave-uniform), x coherent loads with
// depth-8 register prefetch. Reads up to 15 rows past panel (guarded).
template<int NR, int NK>
__device__ __forceinline__ void gemv_pf(float* acc, const float* __restrict__ Wl,
                                        const float* Xg, int b) {
    const float* Xp = Xg + b;
    float xa[4], xb[4];
#pragma unroll
    for (int u = 0; u < 4; ++u) xa[u] = cload(Xp + u * 64);
#pragma unroll
    for (int u = 0; u < 4; ++u) xb[u] = cload(Xp + (4 + u) * 64);
#pragma unroll 1
    for (int k = 0; k < NK; k += 4) {
        float xc[4];
#pragma unroll
        for (int u = 0; u < 4; ++u) xc[u] = cload(Xp + (k + 8 + u) * 64);
#pragma unroll
        for (int u = 0; u < 4; ++u) {
            const float x = xa[u];
            const float4* wp = (const float4*)(Wl + (k + u) * NR);
#pragma unroll
            for (int q = 0; q < NR / 4; ++q) {
                const float4 w = wp[q];
                acc[q * 4 + 0] = fmaf(x, w.x, acc[q * 4 + 0]);
                acc[q * 4 + 1] = fmaf(x, w.y, acc[q * 4 + 1]);
                acc[q * 4 + 2] = fmaf(x, w.z, acc[q * 4 + 2]);
                acc[q * 4 + 3] = fmaf(x, w.w, acc[q * 4 + 3]);
            }
        }
#pragma unroll
        for (int u = 0; u < 4; ++u) { xa[u] = xb[u]; xb[u] = xc[u]; }
    }
}

// FC segment: 4 outputs, x coherent w/ depth-8 prefetch, weights cached WFCT.
__device__ __forceinline__ void fc_seg4(float* f, const float* __restrict__ WT,
                                        const float* Xlane, int k0, int k1, int oc) {
    float xa[4], xb[4];
#pragma unroll
    for (int u = 0; u < 4; ++u) xa[u] = cload(Xlane + (k0 + u) * 64);
#pragma unroll
    for (int u = 0; u < 4; ++u) xb[u] = cload(Xlane + (k0 + 4 + u) * 64);
#pragma unroll 1
    for (int k = k0; k < k1; k += 4) {
        float xc[4];
#pragma unroll
        for (int u = 0; u < 4; ++u) xc[u] = cload(Xlane + (k + 8 + u) * 64);
#pragma unroll
        for (int u = 0; u < 4; ++u) {
            const float4 w = *(const float4*)(WT + (size_t)(k + u) * 128 + oc);
            f[0] = fmaf(xa[u], w.x, f[0]); f[1] = fmaf(xa[u], w.y, f[1]);
            f[2] = fmaf(xa[u], w.z, f[2]); f[3] = fmaf(xa[u], w.w, f[3]);
        }
#pragma unroll
        for (int u = 0; u < 4; ++u) { xa[u] = xb[u]; xb[u] = xc[u]; }
    }
}

// --------------------------- prep kernels ----------------------------------
__global__ void prep_zero4(float4* __restrict__ ws4) {
    int i = blockIdx.x * blockDim.x + threadIdx.x;
    if (i < WS_FCT / 4) ws4[i] = make_float4(0.f, 0.f, 0.f, 0.f);
}

__global__ void prep_strokesT(const float* __restrict__ strokes, float* __restrict__ ws) {
    int idx = blockIdx.x * blockDim.x + threadIdx.x;
    if (idx >= TT * 3 * BB) return;
    int b = idx & 63;
    int tk = idx >> 6;
    int k = tk % 3, t = tk / 3;
    ws[WS_ST + idx] = strokes[((size_t)b * TT + t) * 3 + k];
}

__global__ void prep_fcT(const float* __restrict__ W_fc, float* __restrict__ dst) {
    int idx = blockIdx.x * blockDim.x + threadIdx.x;
    if (idx >= 1536 * 128) return;
    int o = idx & 127, k = idx >> 7;
    dst[idx] = (o < NOUT) ? W_fc[(size_t)o * 1536 + k] : 0.f;
}

// ------------------ grid barrier (2-level, fence-free) ---------------------
__device__ __forceinline__ void gbar(unsigned* base, int blk) {
    __syncthreads();   // drains each wave's (write-through sc1) stores
    if (threadIdx.x == 0) {
        asm volatile("s_waitcnt vmcnt(0) lgkmcnt(0)" ::: "memory");
        unsigned* rcnt = base;
        unsigned* rgen = base + 16;
        unsigned* gcnt = base + 64 + (blk >> 4) * 32;
        unsigned g0 = __hip_atomic_load(rgen, __ATOMIC_RELAXED, __HIP_MEMORY_SCOPE_AGENT);
        if (__hip_atomic_fetch_add(gcnt, 1u, __ATOMIC_RELAXED, __HIP_MEMORY_SCOPE_AGENT) == 15u) {
            __hip_atomic_store(gcnt, 0u, __ATOMIC_RELAXED, __HIP_MEMORY_SCOPE_AGENT);
            if (__hip_atomic_fetch_add(rcnt, 1u, __ATOMIC_RELAXED, __HIP_MEMORY_SCOPE_AGENT) == 15u) {
                __hip_atomic_store(rcnt, 0u, __ATOMIC_RELAXED, __HIP_MEMORY_SCOPE_AGENT);
                __hip_atomic_fetch_add(rgen, 1u, __ATOMIC_RELAXED, __HIP_MEMORY_SCOPE_AGENT);
            }
        }
        while (__hip_atomic_load(rgen, __ATOMIC_RELAXED, __HIP_MEMORY_SCOPE_AGENT) == g0)
            __builtin_amdgcn_s_sleep(1);
        asm volatile("" ::: "memory");
    }
    __syncthreads();
}

// --------------------------- main pipeline ---------------------------------
__global__ void __launch_bounds__(1024, 4)
hand_pipeline(const int* __restrict__ chars, const float* __restrict__ chars_mask,
              const float* __restrict__ W_att, const float* __restrict__ b_att,
              const float* __restrict__ Wih0, const float* __restrict__ Whh0,
              const float* __restrict__ b0,
              const float* __restrict__ Wih1, const float* __restrict__ Whh1,
              const float* __restrict__ b1,
              const float* __restrict__ Wih2, const float* __restrict__ Whh2,
              const float* __restrict__ b2,
              const float* __restrict__ b_fc,
              float* ws, float* __restrict__ out) {
    __shared__ float smem[L_TOT];
    float* REDA  = smem + L_REDA;
    float* REDB  = smem + L_REDB;
    float* GATES = smem + L_GATE;
    float* HCOL  = smem + L_REDA;          // alias: free after P2 reduce
    float* KAP   = smem + L_KAP;
    float* ABK   = smem + L_ABK;
    float* PHI   = smem + L_PHI;
    float* MSK   = smem + L_MSK;
    int*   CHS   = (int*)(smem + L_CHS);

    const int tid = threadIdx.x;
    const int blk = blockIdx.x;
    const int b   = tid & 63;
    const int wv  = __builtin_amdgcn_readfirstlane(tid >> 6);
    unsigned* bar = (unsigned*)ws;
    const bool fcb = (blk >= 64 && blk < 80);
    const int o0 = (blk - 64) * 8;

    // ---- one-time LDS weight fill ----
    for (int idx = tid; idx < L_REDA; idx += 1024) {
        float v = 0.f;
        if (idx < L_WB) {                       // WA [w][76][16]: k=74w+i of [w|h0]
            int w = idx / 1216, rem = idx - w * 1216;
            int i = rem >> 4, c = rem & 15;
            int k = 74 * w + i;
            int hu = (c >> 2) & 1, g = c & 3;
            int grow = g * HH + blk * 2 + hu;
            if (i < 74) {
                if (c < 8) v = (k < 80) ? Wih0[grow * 83 + 3 + k]
                                        : Whh0[(size_t)grow * 512 + (k - 80)];
                else       v = Wih1[(size_t)grow * 595 + 3 + k];
            }
        } else if (idx < L_WD1) {               // WB [v][64][8]: Whh1
            int j2 = idx - L_WB;
            int vv = j2 >> 9, rem = j2 & 511;
            int i = rem >> 3, c = rem & 7;
            int hu = c >> 2, g = c & 3;
            int grow = g * HH + blk * 2 + hu;
            v = Whh1[(size_t)grow * 512 + vv * 64 + i];
        } else if (idx < L_WD2) {               // WD1 [w][76][8]: L2 over [w|h1]
            int j3 = idx - L_WD1;
            int w = j3 / 608, rem = j3 - w * 608;
            int i = rem >> 3, c = rem & 7;
            int k = 74 * w + i;
            int hu = c >> 2, g = c & 3;
            int grow = g * HH + blk * 2 + hu;
            if (i < 74) v = Wih2[(size_t)grow * 595 + 3 + k];
        } else if (idx < L_WST) {               // WD2 [v][64][8]: Whh2
            int j4 = idx - L_WD2;
            int vv = j4 >> 9, rem = j4 & 511;
            int i = rem >> 3, c = rem & 7;
            int hu = c >> 2, g = c & 3;
            int grow = g * HH + blk * 2 + hu;
            v = Whh2[(size_t)grow * 512 + vv * 64 + i];
        } else {                                // WST [lay][3][8]
            int j6 = idx - L_WST;
            if (j6 < 72) {
                int lay = j6 / 24, rem = j6 - lay * 24;
                int kk = rem >> 3, c = rem & 7;
                int hu = c >> 2, g = c & 3;
                int grow = g * HH + blk * 2 + hu;
                v = (lay == 0) ? Wih0[grow * 83 + kk]
                  : (lay == 1) ? Wih1[(size_t)grow * 595 + kk]
                               : Wih2[(size_t)grow * 595 + kk];
            }
        }
        smem[idx] = v;
    }
    if (blk < 64) {
        if (tid < 100) { CHS[tid] = chars[blk * UU + tid]; MSK[tid] = chars_mask[blk * UU + tid]; }
        if (tid < 16) KAP[tid] = 0.f;
    }
    __syncthreads();

    float cL = 0.f;   // tid<128: L0 cell; tid 128..255: L1 cell
    float c2 = 0.f;   // tid<128: L2 cell

    for (int s = 0; s <= TT + 1; ++s) {
        const int cur = s & 3, sl = (s - 1) & 3, sl2 = (s - 2) & 3;

        // ================= P1: L0(t=s) + L1(t=s-1) ==========================
        if (s <= TT) {
            if (wv < 8) {          // JA: 16 rows over XA[sl] = [w|h0]_{s-1}
                float acc[16];
#pragma unroll
                for (int r = 0; r < 16; ++r) acc[r] = 0.f;
                gemv_pf<16, 76>(acc, smem + L_WA + wv * 1216,
                                ws + WS_XA + sl * XASZ + 74 * wv * 64, b);
#pragma unroll
                for (int r = 0; r < 16; ++r) REDA[wv * 1024 + r * 64 + b] = acc[r];
            } else {               // JB: 8 rows (L1) over h1_{s-2}
                const int v = wv - 8;
                float acc[8];
#pragma unroll
                for (int r = 0; r < 8; ++r) acc[r] = 0.f;
                gemv_pf<8, 64>(acc, smem + L_WB + v * 512,
                               ws + WS_XB + sl2 * XASZ + (80 + 64 * v) * 64, b);
#pragma unroll
                for (int r = 0; r < 8; ++r) REDB[v * 512 + r * 64 + b] = acc[r];
            }
            __syncthreads();
            {   // reduce: wave wv owns gate row wv; fold strokes + bias
                const int r = wv, rl = r & 7, hu = rl >> 2, g = rl & 3;
                const int bi = g * HH + blk * 2 + hu;
                const int lay = r >> 3;
                float sum;
                int ts;
                if (r < 8) { sum = b0[bi]; ts = (s < TT) ? s : TT - 1; }
                else       { sum = b1[bi]; ts = (s >= 1) ? s - 1 : 0; }
                const float* st = ws + WS_ST + ts * 192 + b;
#pragma unroll
                for (int kk = 0; kk < 3; ++kk)
                    sum = fmaf(st[kk * 64], smem[L_WST + lay * 24 + kk * 8 + rl], sum);
#pragma unroll
                for (int w = 0; w < 8; ++w) sum += REDA[w * 1024 + r * 64 + b];
                if (r >= 8) {
#pragma unroll
                    for (int v = 0; v < 8; ++v) sum += REDB[v * 512 + rl * 64 + b];
                }
                GATES[r * 64 + b] = sum;
            }
            __syncthreads();
            if (tid < 256) {   // cells: L0 (tid<128), L1 (tid 128..255)
                const int lay = tid >> 7, hu = (tid >> 6) & 1, bb = tid & 63;
                const bool act = (lay == 0) ? (s < TT) : (s >= 1);
                if (act) {
                    const int r0 = lay * 8 + hu * 4;
                    const float gi = GATES[(r0 + 0) * 64 + bb];
                    const float gf = GATES[(r0 + 1) * 64 + bb];
                    const float gg = GATES[(r0 + 2) * 64 + bb];
                    const float go = GATES[(r0 + 3) * 64 + bb];
                    cL = sigmf(gf) * cL + sigmf(gi) * tanhf_(gg);
                    const float h = sigmf(go) * tanhf_(cL);
                    const int row = 80 + blk * 2 + hu;
                    if (lay == 0) cstore(ws + WS_XA + cur * XASZ + row * 64 + bb, h);
                    else          cstore(ws + WS_XB + sl  * XASZ + row * 64 + bb, h);
                }
            }
        }
        gbar(bar, blk);

        // ================= P2: L2(t=s-1) + FC(t=s-2) + ATT(t=s) ============
        {
            if (s <= TT) {         // JD: 8 rows over XB[sl] + h2_{s-2}
                float acc[8];
#pragma unroll
                for (int r = 0; r < 8; ++r) acc[r] = 0.f;
                if (wv < 8) {
                    gemv_pf<8, 76>(acc, smem + L_WD1 + wv * 608,
                                   ws + WS_XB + sl * XASZ + 74 * wv * 64, b);
                } else {
                    const int v = wv - 8;
                    gemv_pf<8, 64>(acc, smem + L_WD2 + v * 512,
                                   ws + WS_H2 + sl2 * H2SZ + 64 * v * 64, b);
                }
#pragma unroll
                for (int r = 0; r < 8; ++r) REDA[wv * 512 + r * 64 + b] = acc[r];
            }
            if (fcb && s >= 2) {   // FC partials: 4 outputs, 192-k slice
                const int half = wv & 1;
                const int oc = o0 + half * 4;
                const int ks = (wv >> 1) * 192, ke = ks + 192;
                const float* WT = ws + WS_FCT;
                float f[4] = {0.f, 0.f, 0.f, 0.f};
                const float* X0 = ws + WS_XA + sl2 * XASZ + 80 * 64 + b;
                const float* X1 = ws + WS_XB + sl2 * XASZ + 80 * 64 + b - 512 * 64;
                const float* X2 = ws + WS_H2 + sl2 * H2SZ + b - 1024 * 64;
                int a_ = ks, e_ = min(ke, 512);
                if (a_ < e_) fc_seg4(f, WT, X0, a_, e_, oc);
                a_ = max(ks, 512); e_ = min(ke, 1024);
                if (a_ < e_) fc_seg4(f, WT, X1, a_, e_, oc);
                a_ = max(ks, 1024);
                if (a_ < ke) fc_seg4(f, WT, X2, a_, ke, oc);
#pragma unroll
                for (int r = 0; r < 4; ++r) REDB[wv * 256 + r * 64 + b] = f[r];
            }
            __syncthreads();
            if (wv < 8) {          // L2 gate reduce
                const int rl = wv, hu = rl >> 2, g = rl & 3;
                float sum = b2[g * HH + blk * 2 + hu];
                const int ts = (s >= 1) ? s - 1 : 0;
                const float* st = ws + WS_ST + ts * 192 + b;
#pragma unroll
                for (int kk = 0; kk < 3; ++kk)
                    sum = fmaf(st[kk * 64], smem[L_WST + 2 * 24 + kk * 8 + rl], sum);
#pragma unroll
                for (int w = 0; w < 16; ++w) sum += REDA[w * 512 + rl * 64 + b];
                GATES[rl * 64 + b] = sum;
            } else if (fcb && s >= 2) {   // FC reduce + store (waves 8..15)
                const int l = wv - 8;
                const int half = l >> 2, r = l & 3;
                const int o = o0 + l;
                if (o < NOUT) {
                    float sum = b_fc[o];
#pragma unroll
                    for (int i = 0; i < 8; ++i) sum += REDB[(2 * i + half) * 256 + r * 64 + b];
                    out[((size_t)b * TT + (s - 2)) * NOUT + o] = sum;
                }
            }
            __syncthreads();
            if (tid < 128 && s >= 1 && s <= TT) {    // L2 cell -> H2[sl]
                const int hu = tid >> 6, bb = tid & 63;
                const float gi = GATES[(hu * 4 + 0) * 64 + bb];
                const float gf = GATES[(hu * 4 + 1) * 64 + bb];
                const float gg = GATES[(hu * 4 + 2) * 64 + bb];
                const float go = GATES[(hu * 4 + 3) * 64 + bb];
                c2 = sigmf(gf) * c2 + sigmf(gi) * tanhf_(gg);
                cstore(ws + WS_H2 + sl * H2SZ + (blk * 2 + hu) * 64 + bb, sigmf(go) * tanhf_(c2));
            }
            if (blk < 64 && s < TT) {                // ATT (block = batch)
                __syncthreads();                     // REDA free -> HCOL
                if (tid < 512) HCOL[tid] = cload(ws + WS_XA + cur * XASZ + (80 + tid) * 64 + blk);
                __syncthreads();
                if (tid < 480) {
                    const int a = tid >> 4, p = tid & 15;
                    const float4* wa = (const float4*)(W_att + a * HH + p * 32);
                    const float* hc = HCOL + p * 32;
                    float d = 0.f;
#pragma unroll
                    for (int n = 0; n < 8; ++n) {
                        const float4 w4 = wa[n];
                        d = fmaf(hc[n * 4 + 0], w4.x, fmaf(hc[n * 4 + 1], w4.y,
                            fmaf(hc[n * 4 + 2], w4.z, fmaf(hc[n * 4 + 3], w4.w, d))));
                    }
                    d += __shfl_down(d, 8, 16);
                    d += __shfl_down(d, 4, 16);
                    d += __shfl_down(d, 2, 16);
                    d += __shfl_down(d, 1, 16);
                    if (p == 0) ABK[a] = __expf(d + b_att[a]);
                }
                __syncthreads();
                if (tid < 10) { const float kv = ABK[20 + tid] * 0.05f + KAP[tid]; KAP[tid] = kv; }
                __syncthreads();
                if (tid < 100) {
                    const float u = (float)tid;
                    float ph = 0.f;
#pragma unroll
                    for (int ka = 0; ka < 10; ++ka) {
                        const float d = KAP[ka] - u;
                        ph += ABK[ka] * __expf(-ABK[10 + ka] * d * d);
                    }
                    PHI[tid] = ph * MSK[tid];
                }
                __syncthreads();
                if (tid < 80) {
                    float wvv = 0.f;
                    for (int u2 = 0; u2 < 100; ++u2)
                        if (CHS[u2] == tid) wvv += PHI[u2] * MSK[u2];
                    cstore(ws + WS_XA + cur * XASZ + tid * 64 + blk, wvv);
                    cstore(ws + WS_XB + cur * XASZ + tid * 64 + blk, wvv);
                }
            }
        }
        gbar(bar, blk);
    }
}

// ------------------------ output postprocessing ----------------------------
__global__ void postproc_kernel(float* __restrict__ out) {
    int row  = blockIdx.x * 8 + (threadIdx.x >> 5);
    int lane = threadIdx.x & 31;
    float* r = out + (size_t)row * NOUT;
    float pv = (lane < 20) ? r[80 + lane] : -1e30f;
    float m = pv;
#pragma unroll
    for (int off = 16; off; off >>= 1) m = fmaxf(m, __shfl_xor(m, off, 32));
    float e = (lane < 20) ? __expf(pv - m) : 0.f;
    float sm = e;
#pragma unroll
    for (int off = 16; off; off >>= 1) sm += __shfl_xor(sm, off, 32);
    float logZ = m + __logf(sm);
    float res[4];
    bool wr[4];
    int ps[4];
#pragma unroll
    for (int i = 0; i < 4; ++i) {
        int p = lane + 32 * i;
        ps[i] = p;
        wr[i] = (p < NOUT);
        float x = 0.f;
        if (p < 20)       x = pv - logZ;
        else if (p < 100) { if (wr[i]) x = r[p - 20]; }
        else if (p < 120) x = tanhf_(r[p]);
        else if (p == 120) x = 1.f / (1.f + __expf(r[120]));
        res[i] = x;
    }
#pragma unroll
    for (int i = 0; i < 4; ++i)
        if (wr[i]) r[ps[i]] = res[i];
}

// ------------------------------- launcher ----------------------------------
extern "C" void kernel_launch(void* const* d_in, const int* in_sizes, int n_in,
                              void* d_out, int out_size, void* d_ws, size_t ws_size,
                              hipStream_t stream) {
    const int*   chars      = (const int*)d_in[0];
    const float* chars_mask = (const float*)d_in[1];
    const float* strokes    = (const float*)d_in[2];
    const float* W_ih0 = (const float*)d_in[4];
    const float* W_hh0 = (const float*)d_in[5];
    const float* b0    = (const float*)d_in[6];
    const float* W_att = (const float*)d_in[7];
    const float* b_att = (const float*)d_in[8];
    const float* W_ih1 = (const float*)d_in[9];
    const float* W_hh1 = (const float*)d_in[10];
    const float* b1    = (const float*)d_in[11];
    const float* W_ih2 = (const float*)d_in[12];
    const float* W_hh2 = (const float*)d_in[13];
    const float* b2    = (const float*)d_in[14];
    const float* W_fc  = (const float*)d_in[15];
    const float* b_fc  = (const float*)d_in[16];
    float* ws  = (float*)d_ws;
    float* out = (float*)d_out;

    prep_zero4<<<(WS_FCT / 4 + 255) / 256, 256, 0, stream>>>((float4*)ws);
    prep_strokesT<<<(TT * 3 * BB + 255) / 256, 256, 0, stream>>>(strokes, ws);
    prep_fcT<<<(1536 * 128 + 255) / 256, 256, 0, stream>>>(W_fc, ws + WS_FCT);

    hand_pipeline<<<256, 1024, 0, stream>>>(chars, chars_mask, W_att, b_att,
                                            W_ih0, W_hh0, b0,
                                            W_ih1, W_hh1, b1,
                                            W_ih2, W_hh2, b2,
                                            b_fc, ws, out);
    postproc_kernel<<<(BB * TT) / 8, 256, 0, stream>>>(out);
}

// Round 6
// 20058.974 us; speedup vs baseline: 14.6458x; 1.9950x over previous
//
#include <hip/hip_runtime.h>

// ---------------------------------------------------------------------------
// HandwritingSynthesisNetwork on MI355X — round 6: MFMA rewrite.
// Persistent kernel, 256 blocks x 1024 threads, 2 grid-barrier phases/step:
//   P1(s): L0 gates (t=s, blocks 0-127) + L1 gates (t=s-1, blocks 128-255)
//   P2(s): L2 (t=s-1, blocks 0-127) + FC (t=s-2, blocks 128-159, k-quarters,
//          atomicAdd) + ATT (t=s, blocks 160-223)
// Gate GEMMs: mfma_f32_16x16x32_bf16. Block = 16 A-rows (4 h x 4 gates
// interleaved: m = hloc*4 + gate) x 64 batch (4 waves = 4 N-tiles of 16).
// C-layout (m89): col=lane&15, row=(lane>>4)*4+reg -> lane's 4 C regs are the
// 4 gates of (hloc=lane>>4, b) => cell update entirely in-register.
// B-panel [1120 k x 64 b] staged to LDS in B-frag layout each phase from
// frag-layout rings in ws (8B agent-coherent loads). A (weights) pre-packed
// to frag layout in ws, read per-lane from L2 (plain cached, static).
// ---------------------------------------------------------------------------

#define TT   800
#define NOUT 121
typedef unsigned long long u64;
typedef unsigned int u32;
typedef __attribute__((ext_vector_type(8))) short short8v;
typedef __attribute__((ext_vector_type(4))) float float4v;

// ---- ws byte offsets ----
#define OFF_BAR 0
#define RSLOT   65536                        // 16 chunks x 4096 B
#define OFF_R0  4096
#define OFF_R1  (OFF_R0 + 4*RSLOT)
#define OFF_R2  (OFF_R1 + 4*RSLOT)
#define RWSLOT  12288                        // 3 chunks
#define OFF_RW  (OFF_R2 + 4*RSLOT)
#define OFF_OV  (OFF_RW + 4*RWSLOT)          // 801 x 4096 (chunk-34 overlay)
#define ABLK    36864                        // 36 chunks x 1024 B per A-tile
#define OFF_WA1 (OFF_OV + 801*4096)          // [256][36][64][8] bf16
#define OFF_WA2 (OFF_WA1 + 256*ABLK)         // [128][36][64][8]
#define OFF_WFC (OFF_WA2 + 128*ABLK)         // [32][12][64][8]
#define OFF_END (OFF_WFC + 32*12*1024)

__device__ __forceinline__ float sigmf(float x) { return 1.f / (1.f + __expf(-x)); }
__device__ __forceinline__ float tanhf_(float x) { return 1.f - 2.f / (1.f + __expf(2.f * x)); }
__device__ __forceinline__ unsigned short f2bf(float x) {
    u32 u = __float_as_uint(x);
    return (unsigned short)((u + 0x7FFFu + ((u >> 16) & 1u)) >> 16);
}
__device__ __forceinline__ float bf2f(u32 s) { return __uint_as_float(s << 16); }

// agent-coherent relaxed loads/stores (sc0 sc1; no cache-wide fences)
__device__ __forceinline__ u64 cl64(const u64* p) {
    return __hip_atomic_load(p, __ATOMIC_RELAXED, __HIP_MEMORY_SCOPE_AGENT);
}
__device__ __forceinline__ u32 cl32(const u32* p) {
    return __hip_atomic_load(p, __ATOMIC_RELAXED, __HIP_MEMORY_SCOPE_AGENT);
}
__device__ __forceinline__ void cs32(u32* p, u32 v) {
    __hip_atomic_store(p, v, __ATOMIC_RELAXED, __HIP_MEMORY_SCOPE_AGENT);
}

// --------------------------- prep kernels ----------------------------------
__global__ void prep_zero(u32* ws32) {          // barrier + rings + RW
    int n = (OFF_OV - OFF_BAR) / 4;
    for (int i = blockIdx.x * blockDim.x + threadIdx.x; i < n; i += gridDim.x * blockDim.x)
        ws32[i] = 0u;
}
__global__ void prep_outz(float* out) {
    int n = 64 * TT * NOUT;
    for (int i = blockIdx.x * blockDim.x + threadIdx.x; i < n; i += gridDim.x * blockDim.x)
        out[i] = 0.f;
}
// overlay: chunk-34 frag image per step s: st_{s-1}@k1104-1106, st_s@k1107-1109
__global__ void prep_ov(const float* __restrict__ strokes, short* __restrict__ dst) {
    int n = 801 * 2048;
    for (int idx = blockIdx.x * blockDim.x + threadIdx.x; idx < n; idx += gridDim.x * blockDim.x) {
        int s = idx >> 11, rem = idx & 2047;
        int t = rem >> 9, lane = (rem >> 3) & 63, j = rem & 7;
        int k = 1088 + (lane >> 4) * 8 + j;
        int b = t * 16 + (lane & 15);
        short v = 0;
        int tt = -1, d = 0;
        if (k >= 1104 && k <= 1106)      { tt = s - 1; d = k - 1104; }
        else if (k >= 1107 && k <= 1109) { tt = s;     d = k - 1107; }
        if (tt >= 0 && tt < TT) v = (short)f2bf(strokes[((size_t)b * TT + tt) * 3 + d]);
        dst[idx] = v;
    }
}
// WA1: A-frags for P1 (blk<128: L0; else L1). m=lane&15 -> gate=m&3, hloc=m>>2.
__global__ void prep_wa1(const float* __restrict__ Wih0, const float* __restrict__ Whh0,
                         const float* __restrict__ Wih1, const float* __restrict__ Whh1,
                         short* __restrict__ dst) {
    int n = 256 * 36 * 512;
    for (int idx = blockIdx.x * blockDim.x + threadIdx.x; idx < n; idx += gridDim.x * blockDim.x) {
        int blk = idx / 18432, rem = idx % 18432;
        int c = rem >> 9, r2 = rem & 511, lane = r2 >> 3, j = r2 & 7;
        int m = lane & 15, q = lane >> 4;
        int k = c * 32 + q * 8 + j;
        int gate = m & 3, hloc = m >> 2;
        float v = 0.f;
        if (blk < 128) {
            int grow = gate * 512 + blk * 4 + hloc;
            if (k >= 512 && k < 1024)       v = Whh0[(size_t)grow * 512 + (k - 512)];
            else if (k >= 1024 && k < 1104) v = Wih0[(size_t)grow * 83 + 3 + (k - 1024)];
            else if (k >= 1107 && k < 1110) v = Wih0[(size_t)grow * 83 + (k - 1107)];
        } else {
            int grow = gate * 512 + (blk - 128) * 4 + hloc;
            if (k < 512)        v = Whh1[(size_t)grow * 512 + k];
            else if (k < 1024)  v = Wih1[(size_t)grow * 595 + 83 + (k - 512)];
            else if (k < 1104)  v = Wih1[(size_t)grow * 595 + 3 + (k - 1024)];
            else if (k < 1107)  v = Wih1[(size_t)grow * 595 + (k - 1104)];
        }
        dst[idx] = (short)f2bf(v);
    }
}
__global__ void prep_wa2(const float* __restrict__ Wih2, const float* __restrict__ Whh2,
                         short* __restrict__ dst) {
    int n = 128 * 36 * 512;
    for (int idx = blockIdx.x * blockDim.x + threadIdx.x; idx < n; idx += gridDim.x * blockDim.x) {
        int blk = idx / 18432, rem = idx % 18432;
        int c = rem >> 9, r2 = rem & 511, lane = r2 >> 3, j = r2 & 7;
        int m = lane & 15, q = lane >> 4;
        int k = c * 32 + q * 8 + j;
        int grow = (m & 3) * 512 + blk * 4 + (m >> 2);
        float v = 0.f;
        if (k < 512)        v = Whh2[(size_t)grow * 512 + k];
        else if (k < 1024)  v = Wih2[(size_t)grow * 595 + 83 + (k - 512)];
        else if (k < 1104)  v = Wih2[(size_t)grow * 595 + 3 + (k - 1024)];
        else if (k < 1107)  v = Wih2[(size_t)grow * 595 + (k - 1104)];
        dst[idx] = (short)f2bf(v);
    }
}
__global__ void prep_wfc(const float* __restrict__ W_fc, short* __restrict__ dst) {
    int n = 32 * 12 * 512;
    for (int idx = blockIdx.x * blockDim.x + threadIdx.x; idx < n; idx += gridDim.x * blockDim.x) {
        int fcb = idx / 6144, rem = idx % 6144;
        int c = rem >> 9, r2 = rem & 511, lane = r2 >> 3, j = r2 & 7;
        int o = (fcb >> 2) * 16 + (lane & 15);
        int k = (fcb & 3) * 384 + c * 32 + (lane >> 4) * 8 + j;
        float v = (o < NOUT) ? W_fc[(size_t)o * 1536 + k] : 0.f;
        dst[idx] = (short)f2bf(v);
    }
}

// ------------------ grid barrier (2-level, fence-free) ---------------------
__device__ __forceinline__ void gbar(u32* base, int blk) {
    asm volatile("s_waitcnt vmcnt(0)" ::: "memory");   // drain this wave's stores
    __syncthreads();
    if (threadIdx.x == 0) {
        u32* rcnt = base;
        u32* rgen = base + 16;
        u32* gcnt = base + 64 + (blk >> 4) * 32;
        u32 g0 = __hip_atomic_load(rgen, __ATOMIC_RELAXED, __HIP_MEMORY_SCOPE_AGENT);
        if (__hip_atomic_fetch_add(gcnt, 1u, __ATOMIC_RELAXED, __HIP_MEMORY_SCOPE_AGENT) == 15u) {
            __hip_atomic_store(gcnt, 0u, __ATOMIC_RELAXED, __HIP_MEMORY_SCOPE_AGENT);
            if (__hip_atomic_fetch_add(rcnt, 1u, __ATOMIC_RELAXED, __HIP_MEMORY_SCOPE_AGENT) == 15u) {
                __hip_atomic_store(rcnt, 0u, __ATOMIC_RELAXED, __HIP_MEMORY_SCOPE_AGENT);
                __hip_atomic_fetch_add(rgen, 1u, __ATOMIC_RELAXED, __HIP_MEMORY_SCOPE_AGENT);
            }
        }
        while (__hip_atomic_load(rgen, __ATOMIC_RELAXED, __HIP_MEMORY_SCOPE_AGENT) == g0)
            __builtin_amdgcn_s_sleep(1);
        asm volatile("" ::: "memory");
    }
    __syncthreads();
}

// --------------------------- main pipeline ---------------------------------
__global__ void __launch_bounds__(1024, 4)
hand_pipeline(const int* __restrict__ chars, const float* __restrict__ chars_mask,
              const float* __restrict__ W_att, const float* __restrict__ b_att,
              const float* __restrict__ b0, const float* __restrict__ b1,
              const float* __restrict__ b2, const float* __restrict__ b_fc,
              float* ws, float* __restrict__ out) {
    __shared__ short panel[36 * 4 * 64 * 8];   // 147,456 B: B-frags [chunk][ntile][lane][8]
    __shared__ float KAP[16];
    __shared__ int   CHS[112];
    __shared__ float MSK[112];
    float* pf = (float*)panel;                 // ATT scratch aliases panel

    char* wsB = (char*)ws;
    u32* bar = (u32*)(wsB + OFF_BAR);
    const int tid = threadIdx.x;
    const int blk = blockIdx.x;
    const int lid = tid & 63;
    const int wv  = __builtin_amdgcn_readfirstlane(tid >> 6);
    const int q   = lid >> 4, nn = lid & 15;

    const short* WA1 = (const short*)(wsB + OFF_WA1) + (size_t)blk * 18432;
    const short* WA2 = (const short*)(wsB + OFF_WA2) + (size_t)blk * 18432;   // blk<128 only
    const int fcb = blk - 128;                          // FC role id (0..31)
    const short* WFC = (const short*)(wsB + OFF_WFC) + (size_t)(fcb & 31) * 6144;
    const int ab = blk - 160;                           // ATT batch (0..63)

    // per-lane gate biases (waves 0-3)
    float biasP1[4] = {0,0,0,0}, biasP2[4] = {0,0,0,0};
    if (wv < 4) {
        int hglob = (blk & 127) * 4 + q;
        for (int r = 0; r < 4; ++r) {
            biasP1[r] = (blk < 128 ? b0 : b1)[r * 512 + hglob];
            if (blk < 128) biasP2[r] = b2[r * 512 + hglob];
        }
    }
    if (blk >= 160 && blk < 224) {
        if (tid < 100) { CHS[tid] = chars[ab * 100 + tid]; MSK[tid] = chars_mask[ab * 100 + tid]; }
        if (tid < 16) KAP[tid] = 0.f;
    }
    for (int i = tid; i < 18432; i += 1024) ((u64*)panel)[i] = 0ull;   // incl. pad chunk 35
    __syncthreads();

    float cst1 = 0.f;   // P1 cell (L0 or L1), waves 0-3
    float cst2 = 0.f;   // P2 cell (L2), waves 0-3, blk<128

    for (int s = 0; s <= TT + 1; ++s) {
        // ======================= P1: L0(s) / L1(s-1) ========================
        {
            const bool isL0 = (blk < 128);
            const bool act = isL0 ? (s < TT) : (s >= 1 && s <= TT);
            if (act) {
                const u64* sA = (const u64*)(wsB + OFF_R1 + ((s + 2) & 3) * RSLOT);  // h1_{s-2}
                const u64* sB = (const u64*)(wsB + OFF_R0 + ((s + 3) & 3) * RSLOT);  // h0_{s-1}
                const u64* sW = (const u64*)(wsB + OFF_RW + ((s + 3) & 3) * RWSLOT); // w_{s-1}
                const u64* sO = (const u64*)(wsB + OFF_OV + (size_t)s * 4096);
                const int u0 = isL0 ? 8192 : 0;
                for (int u = u0 + tid; u < 17920; u += 1024) {
                    u64 v;
                    if (u < 8192)       v = cl64(sA + u);
                    else if (u < 16384) v = cl64(sB + (u - 8192));
                    else if (u < 17408) v = cl64(sW + (u - 16384));
                    else                v = cl64(sW + (u - 16384)) | sO[u - 17408];
                    ((u64*)panel)[u] = v;
                }
            }
            __syncthreads();
            if (act && wv < 4) {
                const int c0 = isL0 ? 16 : 0, cN = 36;
                float4v acc = {0.f, 0.f, 0.f, 0.f};
                const short* Ab = WA1 + lid * 8;
                short8v ar0 = *(const short8v*)(Ab + (c0 + 0) * 512);
                short8v ar1 = *(const short8v*)(Ab + (c0 + 1) * 512);
                short8v ar2 = *(const short8v*)(Ab + (c0 + 2) * 512);
                short8v ar3 = *(const short8v*)(Ab + (c0 + 3) * 512);
#pragma unroll 1
                for (int c = c0; c < cN; c += 4) {
                    short8v bv;
                    bv = *(const short8v*)&panel[(((c + 0) * 4 + wv) * 64 + lid) * 8];
                    acc = __builtin_amdgcn_mfma_f32_16x16x32_bf16(ar0, bv, acc, 0, 0, 0);
                    if (c + 4 < cN) ar0 = *(const short8v*)(Ab + (c + 4) * 512);
                    bv = *(const short8v*)&panel[(((c + 1) * 4 + wv) * 64 + lid) * 8];
                    acc = __builtin_amdgcn_mfma_f32_16x16x32_bf16(ar1, bv, acc, 0, 0, 0);
                    if (c + 5 < cN) ar1 = *(const short8v*)(Ab + (c + 5) * 512);
                    bv = *(const short8v*)&panel[(((c + 2) * 4 + wv) * 64 + lid) * 8];
                    acc = __builtin_amdgcn_mfma_f32_16x16x32_bf16(ar2, bv, acc, 0, 0, 0);
                    if (c + 6 < cN) ar2 = *(const short8v*)(Ab + (c + 6) * 512);
                    bv = *(const short8v*)&panel[(((c + 3) * 4 + wv) * 64 + lid) * 8];
                    acc = __builtin_amdgcn_mfma_f32_16x16x32_bf16(ar3, bv, acc, 0, 0, 0);
                    if (c + 7 < cN) ar3 = *(const short8v*)(Ab + (c + 7) * 512);
                }
                // cell update: lane = (hloc=q, b=wv*16+nn); regs = i,f,g,o
                float gi = acc[0] + biasP1[0], gf = acc[1] + biasP1[1];
                float gg = acc[2] + biasP1[2], go = acc[3] + biasP1[3];
                cst1 = sigmf(gf) * cst1 + sigmf(gi) * tanhf_(gg);
                float h = sigmf(go) * tanhf_(cst1);
                u32 hb = f2bf(h);
                u32 other = (u32)__shfl((int)hb, (lid + 16) & 63, 64);
                if (!(q & 1)) {
                    int k = (blk & 127) * 4 + q;
                    char* slot = wsB + (isL0 ? OFF_R0 + (s & 3) * RSLOT
                                             : OFF_R1 + ((s + 3) & 3) * RSLOT);
                    int ck = k >> 5, qq = (k >> 3) & 3, j = k & 7;
                    u32* dst = (u32*)(slot + ((((ck * 4 + wv) * 64 + qq * 16 + nn) * 8 + j) * 2));
                    cs32(dst, hb | (other << 16));
                }
            }
        }
        gbar(bar, blk);

        // ============ P2: L2(s-1) / FC(s-2) / ATT(s) ========================
        if (blk < 128) {                    // ---- L2 ----
            const bool act = (s >= 1 && s <= TT);
            if (act) {
                const u64* sA = (const u64*)(wsB + OFF_R2 + ((s + 2) & 3) * RSLOT);  // h2_{s-2}
                const u64* sB = (const u64*)(wsB + OFF_R1 + ((s + 3) & 3) * RSLOT);  // h1_{s-1}
                const u64* sW = (const u64*)(wsB + OFF_RW + ((s + 3) & 3) * RWSLOT);
                const u64* sO = (const u64*)(wsB + OFF_OV + (size_t)s * 4096);
                for (int u = tid; u < 17920; u += 1024) {
                    u64 v;
                    if (u < 8192)       v = cl64(sA + u);
                    else if (u < 16384) v = cl64(sB + (u - 8192));
                    else if (u < 17408) v = cl64(sW + (u - 16384));
                    else                v = cl64(sW + (u - 16384)) | sO[u - 17408];
                    ((u64*)panel)[u] = v;
                }
            }
            __syncthreads();
            if (act && wv < 4) {
                float4v acc = {0.f, 0.f, 0.f, 0.f};
                const short* Ab = WA2 + lid * 8;
                short8v ar0 = *(const short8v*)(Ab + 0 * 512);
                short8v ar1 = *(const short8v*)(Ab + 1 * 512);
                short8v ar2 = *(const short8v*)(Ab + 2 * 512);
                short8v ar3 = *(const short8v*)(Ab + 3 * 512);
#pragma unroll 1
                for (int c = 0; c < 36; c += 4) {
                    short8v bv;
                    bv = *(const short8v*)&panel[(((c + 0) * 4 + wv) * 64 + lid) * 8];
                    acc = __builtin_amdgcn_mfma_f32_16x16x32_bf16(ar0, bv, acc, 0, 0, 0);
                    if (c + 4 < 36) ar0 = *(const short8v*)(Ab + (c + 4) * 512);
                    bv = *(const short8v*)&panel[(((c + 1) * 4 + wv) * 64 + lid) * 8];
                    acc = __builtin_amdgcn_mfma_f32_16x16x32_bf16(ar1, bv, acc, 0, 0, 0);
                    if (c + 5 < 36) ar1 = *(const short8v*)(Ab + (c + 5) * 512);
                    bv = *(const short8v*)&panel[(((c + 2) * 4 + wv) * 64 + lid) * 8];
                    acc = __builtin_amdgcn_mfma_f32_16x16x32_bf16(ar2, bv, acc, 0, 0, 0);
                    if (c + 6 < 36) ar2 = *(const short8v*)(Ab + (c + 6) * 512);
                    bv = *(const short8v*)&panel[(((c + 3) * 4 + wv) * 64 + lid) * 8];
                    acc = __builtin_amdgcn_mfma_f32_16x16x32_bf16(ar3, bv, acc, 0, 0, 0);
                    if (c + 7 < 36) ar3 = *(const short8v*)(Ab + (c + 7) * 512);
                }
                float gi = acc[0] + biasP2[0], gf = acc[1] + biasP2[1];
                float gg = acc[2] + biasP2[2], go = acc[3] + biasP2[3];
                cst2 = sigmf(gf) * cst2 + sigmf(gi) * tanhf_(gg);
                float h = sigmf(go) * tanhf_(cst2);
                u32 hb = f2bf(h);
                u32 other = (u32)__shfl((int)hb, (lid + 16) & 63, 64);
                if (!(q & 1)) {
                    int k = blk * 4 + q;
                    char* slot = wsB + OFF_R2 + ((s + 3) & 3) * RSLOT;
                    int ck = k >> 5, qq = (k >> 3) & 3, j = k & 7;
                    u32* dst = (u32*)(slot + ((((ck * 4 + wv) * 64 + qq * 16 + nn) * 8 + j) * 2));
                    cs32(dst, hb | (other << 16));
                }
            }
        } else if (blk < 160) {             // ---- FC (k-quarter partials) ----
            const bool act = (s >= 2);
            const int kq = fcb & 3, mt = fcb >> 2;
            if (act) {
                const u64* rr0 = (const u64*)(wsB + OFF_R0 + ((s + 2) & 3) * RSLOT);
                const u64* rr1 = (const u64*)(wsB + OFF_R1 + ((s + 2) & 3) * RSLOT);
                const u64* rr2 = (const u64*)(wsB + OFF_R2 + ((s + 2) & 3) * RSLOT);
                const int gb = kq * 6144;
                for (int u = tid; u < 6144; u += 1024) {
                    int g = gb + u;
                    u64 v = (g < 8192) ? cl64(rr0 + g)
                          : (g < 16384) ? cl64(rr1 + (g - 8192))
                                        : cl64(rr2 + (g - 16384));
                    ((u64*)panel)[u] = v;
                }
            }
            __syncthreads();
            if (act && wv < 4) {
                float4v acc = {0.f, 0.f, 0.f, 0.f};
                const short* Ab = WFC + lid * 8;
                short8v ar0 = *(const short8v*)(Ab + 0 * 512);
                short8v ar1 = *(const short8v*)(Ab + 1 * 512);
                short8v ar2 = *(const short8v*)(Ab + 2 * 512);
                short8v ar3 = *(const short8v*)(Ab + 3 * 512);
#pragma unroll 1
                for (int c = 0; c < 12; c += 4) {
                    short8v bv;
                    bv = *(const short8v*)&panel[(((c + 0) * 4 + wv) * 64 + lid) * 8];
                    acc = __builtin_amdgcn_mfma_f32_16x16x32_bf16(ar0, bv, acc, 0, 0, 0);
                    if (c + 4 < 12) ar0 = *(const short8v*)(Ab + (c + 4) * 512);
                    bv = *(const short8v*)&panel[(((c + 1) * 4 + wv) * 64 + lid) * 8];
                    acc = __builtin_amdgcn_mfma_f32_16x16x32_bf16(ar1, bv, acc, 0, 0, 0);
                    if (c + 5 < 12) ar1 = *(const short8v*)(Ab + (c + 5) * 512);
                    bv = *(const short8v*)&panel[(((c + 2) * 4 + wv) * 64 + lid) * 8];
                    acc = __builtin_amdgcn_mfma_f32_16x16x32_bf16(ar2, bv, acc, 0, 0, 0);
                    if (c + 6 < 12) ar2 = *(const short8v*)(Ab + (c + 6) * 512);
                    bv = *(const short8v*)&panel[(((c + 3) * 4 + wv) * 64 + lid) * 8];
                    acc = __builtin_amdgcn_mfma_f32_16x16x32_bf16(ar3, bv, acc, 0, 0, 0);
                    if (c + 7 < 12) ar3 = *(const short8v*)(Ab + (c + 7) * 512);
                }
                const int b = wv * 16 + nn;
#pragma unroll
                for (int r = 0; r < 4; ++r) {
                    int o = mt * 16 + q * 4 + r;
                    if (o < NOUT) {
                        float v = acc[r] + (kq == 0 ? b_fc[o] : 0.f);
                        atomicAdd(out + ((size_t)b * TT + (s - 2)) * NOUT + o, v);
                    }
                }
            }
        } else if (blk < 224) {             // ---- ATT (block = batch ab) ----
            if (s < TT) {
                float* HCOL = pf;            // 512
                float* ABK  = pf + 512;      // 32
                float* PHI  = pf + 544;      // 112
                float* CTX  = pf + 656;      // 80
                const char* r0cur = wsB + OFF_R0 + (s & 3) * RSLOT;
                const int nt = ab >> 4, bn = ab & 15;
                if (tid < 256) {
                    int k = tid * 2;
                    int ck = k >> 5, qq = (k >> 3) & 3, j = k & 7;
                    const u32* src = (const u32*)(r0cur +
                        ((((ck * 4 + nt) * 64 + qq * 16 + bn) * 8 + j) * 2));
                    u32 pv = cl32(src);
                    HCOL[k] = bf2f(pv & 0xFFFF);
                    HCOL[k + 1] = bf2f(pv >> 16);
                }
                __syncthreads();
                if (tid < 480) {
                    const int a = tid >> 4, p = tid & 15;
                    const float4* wa = (const float4*)(W_att + a * 512 + p * 32);
                    const float* hc = HCOL + p * 32;
                    float d = 0.f;
#pragma unroll
                    for (int n2 = 0; n2 < 8; ++n2) {
                        const float4 w4 = wa[n2];
                        d = fmaf(hc[n2 * 4 + 0], w4.x, fmaf(hc[n2 * 4 + 1], w4.y,
                            fmaf(hc[n2 * 4 + 2], w4.z, fmaf(hc[n2 * 4 + 3], w4.w, d))));
                    }
                    d += __shfl_down(d, 8, 16);
                    d += __shfl_down(d, 4, 16);
                    d += __shfl_down(d, 2, 16);
                    d += __shfl_down(d, 1, 16);
                    if (p == 0) ABK[a] = __expf(d + b_att[a]);
                }
                __syncthreads();
                if (tid < 10) { KAP[tid] = ABK[20 + tid] * 0.05f + KAP[tid]; }
                __syncthreads();
                if (tid < 100) {
                    const float u = (float)tid;
                    float ph = 0.f;
#pragma unroll
                    for (int ka = 0; ka < 10; ++ka) {
                        const float d = KAP[ka] - u;
                        ph += ABK[ka] * __expf(-ABK[10 + ka] * d * d);
                    }
                    PHI[tid] = ph * MSK[tid];
                }
                __syncthreads();
                if (tid < 80) {
                    float wvv = 0.f;
                    for (int u2 = 0; u2 < 100; ++u2)
                        if (CHS[u2] == tid) wvv += PHI[u2] * MSK[u2];
                    CTX[tid] = wvv;
                }
                __syncthreads();
                if (tid < 40) {
                    int k = 1024 + tid * 2;
                    int lc = (k - 1024) >> 5, qq = (k >> 3) & 3, j = k & 7;
                    char* slot = wsB + OFF_RW + (s & 3) * RWSLOT;
                    u32* dst = (u32*)(slot + ((((lc * 4 + nt) * 64 + qq * 16 + bn) * 8 + j) * 2));
                    cs32(dst, (u32)f2bf(CTX[tid * 2]) | ((u32)f2bf(CTX[tid * 2 + 1]) << 16));
                }
            }
        }
        gbar(bar, blk);
    }
}

// ------------------------ output postprocessing ----------------------------
__global__ void postproc_kernel(float* __restrict__ out) {
    int row  = blockIdx.x * 8 + (threadIdx.x >> 5);
    int lane = threadIdx.x & 31;
    float* r = out + (size_t)row * NOUT;
    float pv = (lane < 20) ? r[80 + lane] : -1e30f;
    float m = pv;
#pragma unroll
    for (int off = 16; off; off >>= 1) m = fmaxf(m, __shfl_xor(m, off, 32));
    float e = (lane < 20) ? __expf(pv - m) : 0.f;
    float sm = e;
#pragma unroll
    for (int off = 16; off; off >>= 1) sm += __shfl_xor(sm, off, 32);
    float logZ = m + __logf(sm);
    float res[4];
    bool wr[4];
    int ps[4];
#pragma unroll
    for (int i = 0; i < 4; ++i) {
        int p = lane + 32 * i;
        ps[i] = p;
        wr[i] = (p < NOUT);
        float x = 0.f;
        if (p < 20)       x = pv - logZ;
        else if (p < 100) { if (wr[i]) x = r[p - 20]; }
        else if (p < 120) x = tanhf_(r[p]);
        else if (p == 120) x = 1.f / (1.f + __expf(r[120]));
        res[i] = x;
    }
#pragma unroll
    for (int i = 0; i < 4; ++i)
        if (wr[i]) r[ps[i]] = res[i];
}

// ------------------------------- launcher ----------------------------------
extern "C" void kernel_launch(void* const* d_in, const int* in_sizes, int n_in,
                              void* d_out, int out_size, void* d_ws, size_t ws_size,
                              hipStream_t stream) {
    const int*   chars      = (const int*)d_in[0];
    const float* chars_mask = (const float*)d_in[1];
    const float* strokes    = (const float*)d_in[2];
    const float* W_ih0 = (const float*)d_in[4];
    const float* W_hh0 = (const float*)d_in[5];
    const float* b0    = (const float*)d_in[6];
    const float* W_att = (const float*)d_in[7];
    const float* b_att = (const float*)d_in[8];
    const float* W_ih1 = (const float*)d_in[9];
    const float* W_hh1 = (const float*)d_in[10];
    const float* b1    = (const float*)d_in[11];
    const float* W_ih2 = (const float*)d_in[12];
    const float* W_hh2 = (const float*)d_in[13];
    const float* b2    = (const float*)d_in[14];
    const float* W_fc  = (const float*)d_in[15];
    const float* b_fc  = (const float*)d_in[16];
    float* ws  = (float*)d_ws;
    float* out = (float*)d_out;
    char*  wsB = (char*)d_ws;

    prep_zero<<<512, 256, 0, stream>>>((u32*)ws);
    prep_outz<<<512, 256, 0, stream>>>(out);
    prep_ov<<<1024, 256, 0, stream>>>(strokes, (short*)(wsB + OFF_OV));
    prep_wa1<<<2048, 256, 0, stream>>>(W_ih0, W_hh0, W_ih1, W_hh1, (short*)(wsB + OFF_WA1));
    prep_wa2<<<1024, 256, 0, stream>>>(W_ih2, W_hh2, (short*)(wsB + OFF_WA2));
    prep_wfc<<<128, 256, 0, stream>>>(W_fc, (short*)(wsB + OFF_WFC));

    hand_pipeline<<<256, 1024, 0, stream>>>(chars, chars_mask, W_att, b_att,
                                            b0, b1, b2, b_fc, ws, out);
    postproc_kernel<<<(64 * TT) / 8, 256, 0, stream>>>(out);
}